// Round 14
// baseline (1359.234 us; speedup 1.0000x reference)
//
#include <hip/hip_runtime.h>
#include <hip/hip_bf16.h>

#define VOCAB 10000
#define D 200
#define NLAYERS 3
#define NB 16
#define NS 512
#define M 8192        // NB*NS
#define KA 224        // padded K for A (h3 bf16), 7 * 32
#define KB 232        // padded K for fc_w bf16; 29 16B-chunks (odd -> no LDS bank conflicts)
#define NPADA 10120   // 79*128 = 10112, +8 rows slack for unguarded staging
#define NTILES_N 79

// ws layout (bytes)
#define OFF_BUF0 0u                 // 6,553,600  cells1 (pipe) / h buffer (fallback)
#define OFF_BUF1 6553600u           // 6,553,600  xw0 (layer-0 input proj)
#define OFF_WT   13107200u          //   480,000  w_ih transposed (all layers)
#define OFF_HBF  13587200u          // 3,670,016  h3 bf16 [M][KA]
#define OFF_FWB  17257216u          // 4,695,680  fc_w bf16 [NPADA][KB]
#define OFF_STG1 21952896u          // 6,553,600  cells2
#define WS_NEED  28506496u

typedef __bf16 bf16x8 __attribute__((ext_vector_type(8)));
typedef float  f32x4  __attribute__((ext_vector_type(4)));
typedef unsigned int u32x4 __attribute__((ext_vector_type(4)));

// ---------------- transpose w_ih ----------------
__global__ void k_wtrans(const float* __restrict__ w_ih, float* __restrict__ wt) {
    int i = blockIdx.x * blockDim.x + threadIdx.x;
    if (i < NLAYERS * D * D) {
        int l = i / (D * D);
        int r = i - l * D * D;
        int k = r / D;
        int n = r - k * D;
        wt[i] = w_ih[l * D * D + n * D + k];
    }
}

// ---------------- fc_w -> bf16 padded ----------------
__global__ void k_fcwbf(const float* __restrict__ fc_w, __bf16* __restrict__ fwb) {
    int i = blockIdx.x * blockDim.x + threadIdx.x;
    if (i < NPADA * KB) {
        int n = i / KB;
        int k = i - n * KB;
        float v = (n < VOCAB && k < D) ? fc_w[(size_t)n * D + k] : 0.f;
        fwb[i] = (__bf16)v;
    }
}

// ---------------- h3 -> bf16 padded (fallback path only) ----------------
__global__ void k_hbf2(const float* __restrict__ h, __bf16* __restrict__ hbf) {
    int i = blockIdx.x * blockDim.x + threadIdx.x;
    if (i < M * KA) {
        int m = i / KA;
        int k = i - m * KA;
        float v = (k < D) ? h[(size_t)m * D + k] : 0.f;
        hbf[i] = (__bf16)v;
    }
}

// ---------------- zero helper (cells) ----------------
__global__ void k_zero(u32x4* __restrict__ p, int n4) {
    int i = blockIdx.x * blockDim.x + threadIdx.x;
    if (i < n4) p[i] = u32x4{0u, 0u, 0u, 0u};
}

// ---------------- xw0 = emb[x] @ w_ih0^T + b (embed folded in) ----------------
__global__ void k_xw_emb(const int* __restrict__ x, const float* __restrict__ emb,
                         const float* __restrict__ wt,
                         const float* __restrict__ b_ih, const float* __restrict__ b_hh,
                         float* __restrict__ xw) {
    int m0 = blockIdx.x * 32;
    int n  = threadIdx.x;
    if (n >= D) return;
    float bias = b_ih[n] + b_hh[n];
    for (int g = 0; g < 8; ++g) {
        const float* r0 = emb + (size_t)x[m0 + g * 4 + 0] * D;  // wave-uniform
        const float* r1 = emb + (size_t)x[m0 + g * 4 + 1] * D;
        const float* r2 = emb + (size_t)x[m0 + g * 4 + 2] * D;
        const float* r3 = emb + (size_t)x[m0 + g * 4 + 3] * D;
        float a0 = bias, a1 = bias, a2 = bias, a3 = bias;
        for (int k = 0; k < D; k += 4) {
            #pragma unroll
            for (int kk = 0; kk < 4; ++kk) {
                float w = wt[(k + kk) * D + n];
                a0 += r0[k + kk] * w; a1 += r1[k + kk] * w;
                a2 += r2[k + kk] * w; a3 += r3[k + kk] * w;
            }
        }
        size_t o = (size_t)(m0 + g * 4) * D + n;
        xw[o] = a0; xw[o + D] = a1; xw[o + 2 * D] = a2; xw[o + 3 * D] = a3;
    }
}

// ---------------- generic xw (fallback path, layers 1,2) ----------------
__global__ void k_xw(const float* __restrict__ hin, const float* __restrict__ wt,
                     const float* __restrict__ b_ih, const float* __restrict__ b_hh,
                     float* __restrict__ xw) {
    int m0 = blockIdx.x * 32;
    int n  = threadIdx.x;
    if (n >= D) return;
    float bias = b_ih[n] + b_hh[n];
    for (int g = 0; g < 8; ++g) {
        const float* r0 = hin + (size_t)(m0 + g * 4) * D;
        float a0 = bias, a1 = bias, a2 = bias, a3 = bias;
        for (int k = 0; k < D; k += 4) {
            #pragma unroll
            for (int kk = 0; kk < 4; ++kk) {
                float w = wt[(k + kk) * D + n];
                float h0v = r0[k + kk];
                float h1v = r0[D + k + kk];
                float h2v = r0[2 * D + k + kk];
                float h3v = r0[3 * D + k + kk];
                a0 += h0v * w; a1 += h1v * w; a2 += h2v * w; a3 += h3v * w;
            }
        }
        size_t o = (size_t)(m0 + g * 4) * D + n;
        xw[o] = a0; xw[o + D] = a1; xw[o + 2 * D] = a2; xw[o + 3 * D] = a3;
    }
}

__device__ inline float fast_tanh(float x) {
    x = fminf(fmaxf(x, -15.f), 15.f);
    float e = __expf(2.f * x);
    return (e - 1.f) / (e + 1.f);
}

// unpack 8 bf16 (one b128) -> two f32x4; bf16->f32 is shift/mask, no cvt
__device__ __forceinline__ void unpack8(u32x4 uu, f32x4& A, f32x4& B) {
    A.x = __builtin_bit_cast(float, uu.x << 16);
    A.y = __builtin_bit_cast(float, uu.x & 0xFFFF0000u);
    A.z = __builtin_bit_cast(float, uu.y << 16);
    A.w = __builtin_bit_cast(float, uu.y & 0xFFFF0000u);
    B.x = __builtin_bit_cast(float, uu.z << 16);
    B.y = __builtin_bit_cast(float, uu.z & 0xFFFF0000u);
    B.z = __builtin_bit_cast(float, uu.w << 16);
    B.w = __builtin_bit_cast(float, uu.w & 0xFFFF0000u);
}

// ---------------- pipelined 3-layer scan, bf16-LDS version ----------------
// r14: EXACT r11 structure (512 thr, 8 waves = 2/SIMD, quad q owns rows 2q,
// 2q+1, spin-stage + two lgkm-only barriers/step — the 634us config) with ONE
// change: h stored in LDS as bf16 in per-dg slices of 56 values (112B,
// 16B-aligned). Lane's 52-value slice: 13 ds_read_b128 -> 7. For l>0 that is
// 26 -> 14 reads/lane; LDS pipe 8x26x12=2496 -> 8x14x12=1344 cyc/step (the
// measured r11/r7/r6 bottleneck). Unpack = shift/mask (2 ops per u32).
// Weights padded to 14 f32x4 (pos 52..55 zero) so pad values multiply by 0.
// Precision: only the recurrent LDS copy of h is bf16; cross-layer cells
// carry full f32 (~bits encoding unchanged); contractive tanh + ||W||<1 =>
// no error compounding. r13's R=4 remap (1072us: 1 wave/SIMD latency
// exposure) reverted entirely.
__global__ __attribute__((amdgpu_flat_work_group_size(512, 512),
                          amdgpu_waves_per_eu(2, 2)))
void k_scan_pipe(const float* __restrict__ whh_all,
                 const float* __restrict__ wih_all,   // row-major
                 const float* __restrict__ b_ih,
                 const float* __restrict__ b_hh,
                 const float* __restrict__ xw0,       // [NB][NS][D] (bias incl.)
                 unsigned* __restrict__ cells1,       // h1 handoff [NB][NS][200]
                 unsigned* __restrict__ cells2,       // h2 handoff
                 __bf16* __restrict__ hbf,
                 float* __restrict__ hidden) {
    __shared__ __align__(16) __bf16 hp[2][224];   // 4 slices x 56 bf16
    __shared__ __align__(16) __bf16 hin[224];
    const int bid = blockIdx.x;
    const int l   = bid >> 4;
    const int b   = bid & 15;
    const int t   = threadIdx.x;
    const int q   = t >> 2, dg = t & 3;
    const bool act = (q < 100);          // quads 0..99 cover rows 0..199
    const int  rr  = 2 * q + (dg & 1);   // row this lane selects / writes
    const int  rrl = act ? rr : 0;
    const bool wlane = act && (dg < 2);
    const int  dstart = dg * 52;         // weight k-slice (global, f32)
    const int  lbase  = dg * 56;         // LDS bf16 slice base
    const int  wrow   = act ? (rr / 52) * 56 + (rr % 52) : 0;  // LDS pos of row rr
    const int  sidx   = (t < 200) ? (t / 52) * 56 + (t % 52) : 0;

    f32x4 wh[2][14], wi[2][14];
    #pragma unroll
    for (int j = 0; j < 2; ++j)
        #pragma unroll
        for (int i = 0; i < 14; ++i) {
            wh[j][i] = f32x4{0.f, 0.f, 0.f, 0.f};
            wi[j][i] = f32x4{0.f, 0.f, 0.f, 0.f};
        }
    if (act) {
        #pragma unroll
        for (int j = 0; j < 2; ++j) {
            const float* wr = whh_all + (size_t)l * D * D + (size_t)(2 * q + j) * D + dstart;
            #pragma unroll
            for (int i = 0; i < 11; ++i) wh[j][i] = *(const f32x4*)(wr + 4 * i);
            if (dg < 3) {                // dg==3 has only 44 real weights
                wh[j][11] = *(const f32x4*)(wr + 44);
                wh[j][12] = *(const f32x4*)(wr + 48);
            }
        }
        if (l > 0) {
            #pragma unroll
            for (int j = 0; j < 2; ++j) {
                const float* wr = wih_all + (size_t)l * D * D + (size_t)(2 * q + j) * D + dstart;
                #pragma unroll
                for (int i = 0; i < 11; ++i) wi[j][i] = *(const f32x4*)(wr + 4 * i);
                if (dg < 3) {
                    wi[j][11] = *(const f32x4*)(wr + 44);
                    wi[j][12] = *(const f32x4*)(wr + 48);
                }
            }
        }
    }
    float bias = 0.f;
    if (l > 0 && act) bias = b_ih[l * D + rr] + b_hh[l * D + rr];

    if (t < 224) {
        hp[0][t] = (__bf16)0.f; hp[1][t] = (__bf16)0.f; hin[t] = (__bf16)0.f;
    }
    __syncthreads();

    const float* xrow = xw0 + (size_t)b * NS * D;                 // l==0 only
    const unsigned* cin = (l == 1) ? cells1 + (size_t)b * NS * 200
                        : (l == 2) ? cells2 + (size_t)b * NS * 200 : nullptr;
    unsigned* co = (l == 0) ? cells1 + (size_t)b * NS * 200
                 : (l == 1) ? cells2 + (size_t)b * NS * 200 : nullptr;

    float hn_prev = 0.f;
    float xv_cur = (l == 0) ? xrow[rrl] : 0.f;

    #pragma unroll 1
    for (int s = 0; s < NS; ++s) {
        const int pb = s & 1;
        // stage incoming h (spin on self-announcing f32 cell; store bf16)
        if (l > 0 && t < 200) {
            unsigned v = __hip_atomic_load(cin + (size_t)s * 200 + t,
                                           __ATOMIC_RELAXED, __HIP_MEMORY_SCOPE_AGENT);
            while (v == 0u)
                v = __hip_atomic_load(cin + (size_t)s * 200 + t,
                                      __ATOMIC_RELAXED, __HIP_MEMORY_SCOPE_AGENT);
            hin[sidx] = (__bf16)__builtin_bit_cast(float, ~v);
        }
        asm volatile("s_waitcnt lgkmcnt(0)" ::: "memory");
        __builtin_amdgcn_s_barrier();
        asm volatile("" ::: "memory");

        const __bf16* hro = hp[pb] + lbase;
        const __bf16* hri = hin + lbase;
        f32x4 a0{0.f,0.f,0.f,0.f}, a1{0.f,0.f,0.f,0.f};
        if (l > 0) {
            #pragma unroll
            for (int i = 0; i < 7; ++i) {
                u32x4 uo = *(const u32x4*)(hro + 8 * i);
                u32x4 ui = *(const u32x4*)(hri + 8 * i);
                f32x4 oA, oB, iA, iB;
                unpack8(uo, oA, oB);
                unpack8(ui, iA, iB);
                a0 += oA * wh[0][2*i] + oB * wh[0][2*i+1]
                    + iA * wi[0][2*i] + iB * wi[0][2*i+1];
                a1 += oA * wh[1][2*i] + oB * wh[1][2*i+1]
                    + iA * wi[1][2*i] + iB * wi[1][2*i+1];
            }
        } else {
            #pragma unroll
            for (int i = 0; i < 7; ++i) {
                u32x4 uo = *(const u32x4*)(hro + 8 * i);
                f32x4 oA, oB;
                unpack8(uo, oA, oB);
                a0 += oA * wh[0][2*i] + oB * wh[0][2*i+1];
                a1 += oA * wh[1][2*i] + oB * wh[1][2*i+1];
            }
        }
        float xv;
        if (l == 0) {
            xv = xv_cur;
            const int sp = (s + 1 < NS) ? s + 1 : NS - 1;
            xv_cur = xrow[(size_t)sp * D + rrl];
        } else {
            xv = bias;
        }
        float s0 = (a0.x + a0.y) + (a0.z + a0.w);
        float s1 = (a1.x + a1.y) + (a1.z + a1.w);
        s0 += __shfl_xor(s0, 1);  s0 += __shfl_xor(s0, 2);
        s1 += __shfl_xor(s1, 1);  s1 += __shfl_xor(s1, 2);
        float hn = fast_tanh(xv + ((dg & 1) ? s1 : s0));
        hn_prev = hn;
        if (wlane) {
            hp[pb ^ 1][wrow] = (__bf16)hn;
            if (l < 2) {
                __hip_atomic_store(co + (size_t)s * 200 + rr,
                                   ~__builtin_bit_cast(unsigned, hn),
                                   __ATOMIC_RELAXED, __HIP_MEMORY_SCOPE_AGENT);
            } else {
                hbf[((size_t)b * NS + s) * KA + rr] = (__bf16)hn;
            }
        } else if (l == 2 && t >= 400 && t < 424) {
            hbf[((size_t)b * NS + s) * KA + (t - 200)] = (__bf16)0.f;  // pad cols
        }
        asm volatile("s_waitcnt lgkmcnt(0)" ::: "memory");
        __builtin_amdgcn_s_barrier();
        asm volatile("" ::: "memory");
    }
    if (wlane) hidden[(size_t)l * NB * D + b * D + rr] = hn_prev;
}

// ---------------- VALU scan (r7-verified, fallback path) ----------------
#define STEP(HR, HW, SIDX)                                                  \
    {                                                                       \
        float xv = xv_next;                                                 \
        int snext = (SIDX) + 1 < NS ? (SIDX) + 1 : NS - 1;                  \
        xv_next = xrow[(size_t)snext * D + rrl];                            \
        f32x4 ac0{0.f,0.f,0.f,0.f}, ac1{0.f,0.f,0.f,0.f};                   \
        _Pragma("unroll")                                                   \
        for (int i = 0; i < 13; ++i) {                                      \
            f32x4 h4 = *(const f32x4*)((HR) + 4 * i);                       \
            ac0 += h4 * w4[0][i];                                           \
            ac1 += h4 * w4[1][i];                                           \
        }                                                                   \
        float s0 = (ac0.x + ac0.y) + (ac0.z + ac0.w);                       \
        float s1 = (ac1.x + ac1.y) + (ac1.z + ac1.w);                       \
        s0 += __shfl_xor(s0, 1);  s0 += __shfl_xor(s0, 2);                  \
        s1 += __shfl_xor(s1, 1);  s1 += __shfl_xor(s1, 2);                  \
        float hn = fast_tanh(xv + ((dg & 1) ? s1 : s0));                    \
        hlast = hn;                                                         \
        if (wlane) {                                                        \
            (HW)[rr] = hn;                                                  \
            xrow[(size_t)(SIDX) * D + rr] = hn;                             \
        }                                                                   \
        __syncthreads();                                                    \
    }

__global__ __attribute__((amdgpu_flat_work_group_size(512, 512),
                          amdgpu_waves_per_eu(2, 2)))
void k_scan(const float* __restrict__ whh,
            float* __restrict__ io,
            float* __restrict__ hidden) {
    __shared__ float hp0[208], hp1[208];
    int t  = threadIdx.x;
    int b  = blockIdx.x;
    int q  = t >> 2;
    int dg = t & 3;
    const bool act = (q < 100);
    const int  rr  = 2 * q + (dg & 1);
    const int  rrl = act ? rr : 0;
    const bool wlane = act && (dg < 2);
    const int  dstart = dg * 52;

    f32x4 w4[2][13];
    #pragma unroll
    for (int j = 0; j < 2; ++j)
        #pragma unroll
        for (int i = 0; i < 13; ++i) w4[j][i] = f32x4{0.f, 0.f, 0.f, 0.f};
    if (act) {
        #pragma unroll
        for (int j = 0; j < 2; ++j) {
            const float* wr = whh + (size_t)(2 * q + j) * D + dstart;
            #pragma unroll
            for (int i = 0; i < 11; ++i) w4[j][i] = *(const f32x4*)(wr + 4 * i);
            if (dg < 3) {
                w4[j][11] = *(const f32x4*)(wr + 44);
                w4[j][12] = *(const f32x4*)(wr + 48);
            }
        }
    }
    if (t < 208) { hp0[t] = 0.f; hp1[t] = 0.f; }
    __syncthreads();

    float* xrow = io + (size_t)b * NS * D;
    const float* hr0 = hp0 + dstart;
    const float* hr1 = hp1 + dstart;
    float xv_next = xrow[rrl];
    float hlast = 0.f;

    #pragma unroll 1
    for (int s2 = 0; s2 < NS / 2; ++s2) {
        STEP(hr0, hp1, 2 * s2)
        STEP(hr1, hp0, 2 * s2 + 1)
    }
    if (wlane) hidden[b * D + rr] = hlast;
}

// ---------------- final FC: logits = h3_bf @ fcw_bf^T + fc_b (bf16 MFMA) -----
__global__ __launch_bounds__(256) void k_fc(const __bf16* __restrict__ A,
                                            const __bf16* __restrict__ Bw,
                                            const float* __restrict__ fc_b,
                                            float* __restrict__ Cout) {
    __shared__ __bf16 Bl[3840 * 8];
    int tid = threadIdx.x;
    int wg  = blockIdx.x;
    int mt  = wg / NTILES_N, nt = wg - mt * NTILES_N;
    int m0  = mt * 128, n0 = nt * 128;

    {
        const u32x4* src = (const u32x4*)(Bw + (size_t)n0 * KB);
        u32x4* dst = (u32x4*)Bl;
        u32x4 stg[15];
        #pragma unroll
        for (int it = 0; it < 15; ++it) stg[it] = src[tid + it * 256];
        #pragma unroll
        for (int it = 0; it < 15; ++it) dst[tid + it * 256] = stg[it];
    }
    __syncthreads();

    int lane = tid & 63, wv = tid >> 6;
    int wr = wv >> 1, wc = wv & 1;
    int lr = lane & 15, lq = lane >> 4;
    f32x4 acc[4][4] = {};
    #pragma unroll
    for (int ks = 0; ks < 7; ++ks) {
        bf16x8 af[4], bfr[4];
        #pragma unroll
        for (int i = 0; i < 4; ++i) {
            int arow = m0 + wr * 64 + i * 16 + lr;
            af[i] = *(const bf16x8*)(A + (size_t)arow * KA + (ks * 4 + lq) * 8);
            int brow = wc * 64 + i * 16 + lr;
            bfr[i] = *(const bf16x8*)(Bl + brow * KB + (ks * 4 + lq) * 8);
        }
        #pragma unroll
        for (int i = 0; i < 4; ++i) {
            #pragma unroll
            for (int j = 0; j < 4; ++j) {
                acc[i][j] = __builtin_amdgcn_mfma_f32_16x16x32_bf16(af[i], bfr[j],
                                                                   acc[i][j], 0, 0, 0);
            }
        }
    }
    #pragma unroll
    for (int j = 0; j < 4; ++j) {
        int col = n0 + wc * 64 + j * 16 + lr;
        if (col < VOCAB) {
            float bias = fc_b[col];
            #pragma unroll
            for (int i = 0; i < 4; ++i) {
                #pragma unroll
                for (int r = 0; r < 4; ++r) {
                    int row = m0 + wr * 64 + i * 16 + lq * 4 + r;
                    Cout[(size_t)row * VOCAB + col] = acc[i][j][r] + bias;
                }
            }
        }
    }
}

extern "C" void kernel_launch(void* const* d_in, const int* in_sizes, int n_in,
                              void* d_out, int out_size, void* d_ws, size_t ws_size,
                              hipStream_t stream) {
    const int*   x    = (const int*)  d_in[0];
    const float* emb  = (const float*)d_in[1];
    const float* w_ih = (const float*)d_in[2];
    const float* w_hh = (const float*)d_in[3];
    const float* b_ih = (const float*)d_in[4];
    const float* b_hh = (const float*)d_in[5];
    const float* fc_w = (const float*)d_in[6];
    const float* fc_b = (const float*)d_in[7];
    float* out    = (float*)d_out;
    float* hidden = out + (size_t)M * VOCAB;

    char* ws = (char*)d_ws;
    float*    buf0 = (float*)(ws + OFF_BUF0);
    float*    buf1 = (float*)(ws + OFF_BUF1);
    float*    wt   = (float*)(ws + OFF_WT);
    __bf16*   hbf  = (__bf16*)(ws + OFF_HBF);
    __bf16*   fwb  = (__bf16*)(ws + OFF_FWB);
    unsigned* stg0 = (unsigned*)(ws + OFF_BUF0);   // cells1 (aliases buf0)
    unsigned* stg1 = (unsigned*)(ws + OFF_STG1);   // cells2

    k_wtrans<<<(NLAYERS * D * D + 255) / 256, 256, 0, stream>>>(w_ih, wt);
    k_fcwbf <<<(NPADA * KB + 255) / 256, 256, 0, stream>>>(fc_w, fwb);

    if (ws_size >= WS_NEED) {
        k_xw_emb<<<M / 32, 256, 0, stream>>>(x, emb, wt, b_ih, b_hh, buf1);
        const int nst4 = NB * NS * 200 / 4;
        k_zero<<<(nst4 + 255) / 256, 256, 0, stream>>>((u32x4*)stg0, nst4);
        k_zero<<<(nst4 + 255) / 256, 256, 0, stream>>>((u32x4*)stg1, nst4);
        k_scan_pipe<<<NB * NLAYERS, 512, 0, stream>>>(w_hh, w_ih, b_ih, b_hh,
                                                      buf1, stg0, stg1, hbf, hidden);
    } else {
        // fallback: r7-verified serial path
        k_xw_emb<<<M / 32, 256, 0, stream>>>(x, emb, wt, b_ih, b_hh, buf1);
        k_scan<<<NB, 512, 0, stream>>>(w_hh, buf1, hidden);
        float* cur = buf1;
        float* nxt = buf0;
        for (int l = 1; l < NLAYERS; ++l) {
            k_xw  <<<M / 32, 256, 0, stream>>>(cur, wt + l * D * D,
                                               b_ih + l * D, b_hh + l * D, nxt);
            k_scan<<<NB, 512, 0, stream>>>(w_hh + (size_t)l * D * D, nxt,
                                           hidden + l * NB * D);
            float* tswap = cur; cur = nxt; nxt = tswap;
        }
        k_hbf2<<<(M * KA + 255) / 256, 256, 0, stream>>>(cur, hbf);
    }
    k_fc<<<64 * NTILES_N, 256, 0, stream>>>(hbf, fwb, fc_b, out);
}

// Round 15
// 854.612 us; speedup vs baseline: 1.5905x; 1.5905x over previous
//
#include <hip/hip_runtime.h>
#include <hip/hip_bf16.h>

#define VOCAB 10000
#define D 200
#define NLAYERS 3
#define NB 16
#define NS 512
#define M 8192        // NB*NS
#define KA 224        // padded K for A (h3 bf16), 7 * 32
#define KB 232        // padded K for fc_w bf16; 29 16B-chunks (odd -> no LDS bank conflicts)
#define NPADA 10120   // 79*128 = 10112, +8 rows slack for unguarded staging
#define NTILES_N 79

// ws layout (bytes)
#define OFF_BUF0 0u                 // 6,553,600  cells1 (pipe) / h buffer (fallback)
#define OFF_BUF1 6553600u           // 6,553,600  xw0 (layer-0 input proj)
#define OFF_WT   13107200u          //   480,000  w_ih transposed (all layers)
#define OFF_HBF  13587200u          // 3,670,016  h3 bf16 [M][KA]
#define OFF_FWB  17257216u          // 4,695,680  fc_w bf16 [NPADA][KB]
#define OFF_STG1 21952896u          // 6,553,600  cells2
#define WS_NEED  28506496u

typedef __bf16 bf16x8 __attribute__((ext_vector_type(8)));
typedef float  f32x4  __attribute__((ext_vector_type(4)));
typedef unsigned int u32x4 __attribute__((ext_vector_type(4)));

// ---------------- transpose w_ih ----------------
__global__ void k_wtrans(const float* __restrict__ w_ih, float* __restrict__ wt) {
    int i = blockIdx.x * blockDim.x + threadIdx.x;
    if (i < NLAYERS * D * D) {
        int l = i / (D * D);
        int r = i - l * D * D;
        int k = r / D;
        int n = r - k * D;
        wt[i] = w_ih[l * D * D + n * D + k];
    }
}

// ---------------- fc_w -> bf16 padded ----------------
__global__ void k_fcwbf(const float* __restrict__ fc_w, __bf16* __restrict__ fwb) {
    int i = blockIdx.x * blockDim.x + threadIdx.x;
    if (i < NPADA * KB) {
        int n = i / KB;
        int k = i - n * KB;
        float v = (n < VOCAB && k < D) ? fc_w[(size_t)n * D + k] : 0.f;
        fwb[i] = (__bf16)v;
    }
}

// ---------------- h3 -> bf16 padded (fallback path only) ----------------
__global__ void k_hbf2(const float* __restrict__ h, __bf16* __restrict__ hbf) {
    int i = blockIdx.x * blockDim.x + threadIdx.x;
    if (i < M * KA) {
        int m = i / KA;
        int k = i - m * KA;
        float v = (k < D) ? h[(size_t)m * D + k] : 0.f;
        hbf[i] = (__bf16)v;
    }
}

// ---------------- zero helper ----------------
__global__ void k_zero(u32x4* __restrict__ p, int n4) {
    int i = blockIdx.x * blockDim.x + threadIdx.x;
    if (i < n4) p[i] = u32x4{0u, 0u, 0u, 0u};
}

// ---------------- xw0 = emb[x] @ w_ih0^T + b (embed folded in) ----------------
__global__ void k_xw_emb(const int* __restrict__ x, const float* __restrict__ emb,
                         const float* __restrict__ wt,
                         const float* __restrict__ b_ih, const float* __restrict__ b_hh,
                         float* __restrict__ xw) {
    int m0 = blockIdx.x * 32;
    int n  = threadIdx.x;
    if (n >= D) return;
    float bias = b_ih[n] + b_hh[n];
    for (int g = 0; g < 8; ++g) {
        const float* r0 = emb + (size_t)x[m0 + g * 4 + 0] * D;  // wave-uniform
        const float* r1 = emb + (size_t)x[m0 + g * 4 + 1] * D;
        const float* r2 = emb + (size_t)x[m0 + g * 4 + 2] * D;
        const float* r3 = emb + (size_t)x[m0 + g * 4 + 3] * D;
        float a0 = bias, a1 = bias, a2 = bias, a3 = bias;
        for (int k = 0; k < D; k += 4) {
            #pragma unroll
            for (int kk = 0; kk < 4; ++kk) {
                float w = wt[(k + kk) * D + n];
                a0 += r0[k + kk] * w; a1 += r1[k + kk] * w;
                a2 += r2[k + kk] * w; a3 += r3[k + kk] * w;
            }
        }
        size_t o = (size_t)(m0 + g * 4) * D + n;
        xw[o] = a0; xw[o + D] = a1; xw[o + 2 * D] = a2; xw[o + 3 * D] = a3;
    }
}

// ---------------- generic xw (fallback path, layers 1,2) ----------------
__global__ void k_xw(const float* __restrict__ hin, const float* __restrict__ wt,
                     const float* __restrict__ b_ih, const float* __restrict__ b_hh,
                     float* __restrict__ xw) {
    int m0 = blockIdx.x * 32;
    int n  = threadIdx.x;
    if (n >= D) return;
    float bias = b_ih[n] + b_hh[n];
    for (int g = 0; g < 8; ++g) {
        const float* r0 = hin + (size_t)(m0 + g * 4) * D;
        float a0 = bias, a1 = bias, a2 = bias, a3 = bias;
        for (int k = 0; k < D; k += 4) {
            #pragma unroll
            for (int kk = 0; kk < 4; ++kk) {
                float w = wt[(k + kk) * D + n];
                float h0v = r0[k + kk];
                float h1v = r0[D + k + kk];
                float h2v = r0[2 * D + k + kk];
                float h3v = r0[3 * D + k + kk];
                a0 += h0v * w; a1 += h1v * w; a2 += h2v * w; a3 += h3v * w;
            }
        }
        size_t o = (size_t)(m0 + g * 4) * D + n;
        xw[o] = a0; xw[o + D] = a1; xw[o + 2 * D] = a2; xw[o + 3 * D] = a3;
    }
}

__device__ inline float fast_tanh(float x) {
    x = fminf(fmaxf(x, -15.f), 15.f);
    float e = __expf(2.f * x);
    return (e - 1.f) / (e + 1.f);
}

// ---------------- pipelined 3-layer scan (r11-exact + spin backoff) ----------
// r15: EXACT r11 body (the 634us config; r12 xw-handoff, r13 R=4, r14
// bf16-LDS all regressed and are fully reverted). SINGLE pipe change:
// s_sleep(1) backoff in the spin retry path — steady state (cell already
// set) pays nothing; when iterating, load frequency drops ~20x. Tests the
// r13/r14 post-mortem theory that wave-divergent spin hammering (each iter
// a serial agent-scope L3 RTT, 200 lanes x 32 consumer WGs) is what
// collapsed every faster-consumer variant.
__global__ __attribute__((amdgpu_flat_work_group_size(512, 512),
                          amdgpu_waves_per_eu(2, 2)))
void k_scan_pipe(const float* __restrict__ whh_all,
                 const float* __restrict__ wih_all,
                 const float* __restrict__ b_ih,
                 const float* __restrict__ b_hh,
                 const float* __restrict__ xw0,       // [NB][NS][D] (bias incl.)
                 unsigned* __restrict__ cells1,       // h1 handoff [NB][NS][200]
                 unsigned* __restrict__ cells2,       // h2 handoff
                 __bf16* __restrict__ hbf,
                 float* __restrict__ hidden) {
    __shared__ float hp0[208], hp1[208], hin[208];
    const int bid = blockIdx.x;
    const int l   = bid >> 4;            // 16 blocks per layer; layer 0 first
    const int b   = bid & 15;
    const int t   = threadIdx.x;
    const int q   = t >> 2, dg = t & 3;
    const bool act = (q < 100);
    const int  rr  = 2 * q + (dg & 1);
    const int  rrl = act ? rr : 0;
    const bool wlane = act && (dg < 2);
    const int  dstart = dg * 52;

    f32x4 wh[2][13], wi[2][13];
    #pragma unroll
    for (int j = 0; j < 2; ++j)
        #pragma unroll
        for (int i = 0; i < 13; ++i) {
            wh[j][i] = f32x4{0.f, 0.f, 0.f, 0.f};
            wi[j][i] = f32x4{0.f, 0.f, 0.f, 0.f};
        }
    if (act) {
        #pragma unroll
        for (int j = 0; j < 2; ++j) {
            const float* wr = whh_all + (size_t)l * D * D + (size_t)(2 * q + j) * D + dstart;
            #pragma unroll
            for (int i = 0; i < 11; ++i) wh[j][i] = *(const f32x4*)(wr + 4 * i);
            if (dg < 3) {
                wh[j][11] = *(const f32x4*)(wr + 44);
                wh[j][12] = *(const f32x4*)(wr + 48);
            }
        }
        if (l > 0) {
            #pragma unroll
            for (int j = 0; j < 2; ++j) {
                const float* wr = wih_all + (size_t)l * D * D + (size_t)(2 * q + j) * D + dstart;
                #pragma unroll
                for (int i = 0; i < 11; ++i) wi[j][i] = *(const f32x4*)(wr + 4 * i);
                if (dg < 3) {
                    wi[j][11] = *(const f32x4*)(wr + 44);
                    wi[j][12] = *(const f32x4*)(wr + 48);
                }
            }
        }
    }
    float bias = 0.f;
    if (l > 0 && act) bias = b_ih[l * D + rr] + b_hh[l * D + rr];

    if (t < 208) { hp0[t] = 0.f; hp1[t] = 0.f; hin[t] = 0.f; }
    __syncthreads();

    const float* xrow = xw0 + (size_t)b * NS * D;                 // l==0 only
    const unsigned* sin = (l == 1) ? cells1 + (size_t)b * NS * 200
                        : (l == 2) ? cells2 + (size_t)b * NS * 200 : nullptr;
    unsigned* sout = (l == 0) ? cells1 + (size_t)b * NS * 200
                   : (l == 1) ? cells2 + (size_t)b * NS * 200 : nullptr;

    float hn_prev = 0.f;
    float xv_next = (l == 0) ? xrow[rrl] : 0.f;
    const float* hi = hin + dstart;

    #pragma unroll 1
    for (int s = 0; s < NS; ++s) {
        float xv;
        if (l == 0) {
            xv = xv_next;
            const int sn = (s + 1 < NS) ? s + 1 : NS - 1;
            xv_next = xrow[(size_t)sn * D + rrl];
        } else {
            if (t < 200) {   // spin on self-announcing cell, stage into LDS
                const unsigned* p = sin + (size_t)s * 200 + t;
                unsigned v = __hip_atomic_load(p, __ATOMIC_RELAXED,
                                               __HIP_MEMORY_SCOPE_AGENT);
                while (v == 0u) {
                    __builtin_amdgcn_s_sleep(1);      // backoff: ~20x less hammering
                    v = __hip_atomic_load(p, __ATOMIC_RELAXED,
                                          __HIP_MEMORY_SCOPE_AGENT);
                }
                hin[t] = __builtin_bit_cast(float, ~v);
            }
            asm volatile("s_waitcnt lgkmcnt(0)" ::: "memory");
            __builtin_amdgcn_s_barrier();
            asm volatile("" ::: "memory");
            xv = bias;
        }
        const float* hr = ((s & 1) ? hp1 : hp0) + dstart;
        float* hw = (s & 1) ? hp0 : hp1;
        f32x4 ac0{0.f,0.f,0.f,0.f}, ac1{0.f,0.f,0.f,0.f};
        #pragma unroll
        for (int i = 0; i < 13; ++i) {
            f32x4 h4 = *(const f32x4*)(hr + 4 * i);
            ac0 += h4 * wh[0][i];
            ac1 += h4 * wh[1][i];
        }
        if (l > 0) {
            #pragma unroll
            for (int i = 0; i < 13; ++i) {
                f32x4 g4 = *(const f32x4*)(hi + 4 * i);
                ac0 += g4 * wi[0][i];
                ac1 += g4 * wi[1][i];
            }
        }
        float s0 = (ac0.x + ac0.y) + (ac0.z + ac0.w);
        float s1 = (ac1.x + ac1.y) + (ac1.z + ac1.w);
        s0 += __shfl_xor(s0, 1);  s0 += __shfl_xor(s0, 2);
        s1 += __shfl_xor(s1, 1);  s1 += __shfl_xor(s1, 2);
        float hn = fast_tanh(xv + ((dg & 1) ? s1 : s0));
        hn_prev = hn;
        if (wlane) {
            hw[rr] = hn;
            if (l < 2) {
                __hip_atomic_store(sout + (size_t)s * 200 + rr,
                                   ~__builtin_bit_cast(unsigned, hn),
                                   __ATOMIC_RELAXED, __HIP_MEMORY_SCOPE_AGENT);
            } else {
                hbf[((size_t)b * NS + s) * KA + rr] = (__bf16)hn;
            }
        }
        asm volatile("s_waitcnt lgkmcnt(0)" ::: "memory");
        __builtin_amdgcn_s_barrier();
        asm volatile("" ::: "memory");
    }
    if (wlane) hidden[(size_t)l * NB * D + b * D + rr] = hn_prev;
}

// ---------------- VALU scan (r7-verified, fallback path) ----------------
#define STEP(HR, HW, SIDX)                                                  \
    {                                                                       \
        float xv = xv_next;                                                 \
        int snext = (SIDX) + 1 < NS ? (SIDX) + 1 : NS - 1;                  \
        xv_next = xrow[(size_t)snext * D + rrl];                            \
        f32x4 ac0{0.f,0.f,0.f,0.f}, ac1{0.f,0.f,0.f,0.f};                   \
        _Pragma("unroll")                                                   \
        for (int i = 0; i < 13; ++i) {                                      \
            f32x4 h4 = *(const f32x4*)((HR) + 4 * i);                       \
            ac0 += h4 * w4[0][i];                                           \
            ac1 += h4 * w4[1][i];                                           \
        }                                                                   \
        float s0 = (ac0.x + ac0.y) + (ac0.z + ac0.w);                       \
        float s1 = (ac1.x + ac1.y) + (ac1.z + ac1.w);                       \
        s0 += __shfl_xor(s0, 1);  s0 += __shfl_xor(s0, 2);                  \
        s1 += __shfl_xor(s1, 1);  s1 += __shfl_xor(s1, 2);                  \
        float hn = fast_tanh(xv + ((dg & 1) ? s1 : s0));                    \
        hlast = hn;                                                         \
        if (wlane) {                                                        \
            (HW)[rr] = hn;                                                  \
            xrow[(size_t)(SIDX) * D + rr] = hn;                             \
        }                                                                   \
        __syncthreads();                                                    \
    }

__global__ __attribute__((amdgpu_flat_work_group_size(512, 512),
                          amdgpu_waves_per_eu(2, 2)))
void k_scan(const float* __restrict__ whh,
            float* __restrict__ io,
            float* __restrict__ hidden) {
    __shared__ float hp0[208], hp1[208];
    int t  = threadIdx.x;
    int b  = blockIdx.x;
    int q  = t >> 2;
    int dg = t & 3;
    const bool act = (q < 100);
    const int  rr  = 2 * q + (dg & 1);
    const int  rrl = act ? rr : 0;
    const bool wlane = act && (dg < 2);
    const int  dstart = dg * 52;

    f32x4 w4[2][13];
    #pragma unroll
    for (int j = 0; j < 2; ++j)
        #pragma unroll
        for (int i = 0; i < 13; ++i) w4[j][i] = f32x4{0.f, 0.f, 0.f, 0.f};
    if (act) {
        #pragma unroll
        for (int j = 0; j < 2; ++j) {
            const float* wr = whh + (size_t)(2 * q + j) * D + dstart;
            #pragma unroll
            for (int i = 0; i < 11; ++i) w4[j][i] = *(const f32x4*)(wr + 4 * i);
            if (dg < 3) {
                w4[j][11] = *(const f32x4*)(wr + 44);
                w4[j][12] = *(const f32x4*)(wr + 48);
            }
        }
    }
    if (t < 208) { hp0[t] = 0.f; hp1[t] = 0.f; }
    __syncthreads();

    float* xrow = io + (size_t)b * NS * D;
    const float* hr0 = hp0 + dstart;
    const float* hr1 = hp1 + dstart;
    float xv_next = xrow[rrl];
    float hlast = 0.f;

    #pragma unroll 1
    for (int s2 = 0; s2 < NS / 2; ++s2) {
        STEP(hr0, hp1, 2 * s2)
        STEP(hr1, hp0, 2 * s2 + 1)
    }
    if (wlane) hidden[b * D + rr] = hlast;
}

// ---------------- final FC: logits = h3_bf @ fcw_bf^T + fc_b (bf16 MFMA) -----
// r15: nontemporal C stores (write-once 327MB; keep A/B resident in L2).
__global__ __launch_bounds__(256) void k_fc(const __bf16* __restrict__ A,
                                            const __bf16* __restrict__ Bw,
                                            const float* __restrict__ fc_b,
                                            float* __restrict__ Cout) {
    __shared__ __bf16 Bl[3840 * 8];
    int tid = threadIdx.x;
    int wg  = blockIdx.x;
    int mt  = wg / NTILES_N, nt = wg - mt * NTILES_N;
    int m0  = mt * 128, n0 = nt * 128;

    {
        const u32x4* src = (const u32x4*)(Bw + (size_t)n0 * KB);
        u32x4* dst = (u32x4*)Bl;
        u32x4 stg[15];
        #pragma unroll
        for (int it = 0; it < 15; ++it) stg[it] = src[tid + it * 256];
        #pragma unroll
        for (int it = 0; it < 15; ++it) dst[tid + it * 256] = stg[it];
    }
    __syncthreads();

    int lane = tid & 63, wv = tid >> 6;
    int wr = wv >> 1, wc = wv & 1;
    int lr = lane & 15, lq = lane >> 4;
    f32x4 acc[4][4] = {};
    #pragma unroll
    for (int ks = 0; ks < 7; ++ks) {
        bf16x8 af[4], bfr[4];
        #pragma unroll
        for (int i = 0; i < 4; ++i) {
            int arow = m0 + wr * 64 + i * 16 + lr;
            af[i] = *(const bf16x8*)(A + (size_t)arow * KA + (ks * 4 + lq) * 8);
            int brow = wc * 64 + i * 16 + lr;
            bfr[i] = *(const bf16x8*)(Bl + brow * KB + (ks * 4 + lq) * 8);
        }
        #pragma unroll
        for (int i = 0; i < 4; ++i) {
            #pragma unroll
            for (int j = 0; j < 4; ++j) {
                acc[i][j] = __builtin_amdgcn_mfma_f32_16x16x32_bf16(af[i], bfr[j],
                                                                   acc[i][j], 0, 0, 0);
            }
        }
    }
    #pragma unroll
    for (int j = 0; j < 4; ++j) {
        int col = n0 + wc * 64 + j * 16 + lr;
        if (col < VOCAB) {
            float bias = fc_b[col];
            #pragma unroll
            for (int i = 0; i < 4; ++i) {
                #pragma unroll
                for (int r = 0; r < 4; ++r) {
                    int row = m0 + wr * 64 + i * 16 + lq * 4 + r;
                    __builtin_nontemporal_store(acc[i][j][r] + bias,
                                                &Cout[(size_t)row * VOCAB + col]);
                }
            }
        }
    }
}

extern "C" void kernel_launch(void* const* d_in, const int* in_sizes, int n_in,
                              void* d_out, int out_size, void* d_ws, size_t ws_size,
                              hipStream_t stream) {
    const int*   x    = (const int*)  d_in[0];
    const float* emb  = (const float*)d_in[1];
    const float* w_ih = (const float*)d_in[2];
    const float* w_hh = (const float*)d_in[3];
    const float* b_ih = (const float*)d_in[4];
    const float* b_hh = (const float*)d_in[5];
    const float* fc_w = (const float*)d_in[6];
    const float* fc_b = (const float*)d_in[7];
    float* out    = (float*)d_out;
    float* hidden = out + (size_t)M * VOCAB;

    char* ws = (char*)d_ws;
    float*    buf0 = (float*)(ws + OFF_BUF0);
    float*    buf1 = (float*)(ws + OFF_BUF1);
    float*    wt   = (float*)(ws + OFF_WT);
    __bf16*   hbf  = (__bf16*)(ws + OFF_HBF);
    __bf16*   fwb  = (__bf16*)(ws + OFF_FWB);
    unsigned* stg0 = (unsigned*)(ws + OFF_BUF0);   // cells1 (aliases buf0)
    unsigned* stg1 = (unsigned*)(ws + OFF_STG1);   // cells2

    k_wtrans<<<(NLAYERS * D * D + 255) / 256, 256, 0, stream>>>(w_ih, wt);
    k_fcwbf <<<(NPADA * KB + 255) / 256, 256, 0, stream>>>(fc_w, fwb);

    if (ws_size >= WS_NEED) {
        k_xw_emb<<<M / 32, 256, 0, stream>>>(x, emb, wt, b_ih, b_hh, buf1);
        const int nst4 = NB * NS * 200 / 4;
        const int nhb4 = M * KA * 2 / 16;
        k_zero<<<(nst4 + 255) / 256, 256, 0, stream>>>((u32x4*)stg0, nst4);
        k_zero<<<(nst4 + 255) / 256, 256, 0, stream>>>((u32x4*)stg1, nst4);
        k_zero<<<(nhb4 + 255) / 256, 256, 0, stream>>>((u32x4*)hbf, nhb4);
        k_scan_pipe<<<NB * NLAYERS, 512, 0, stream>>>(w_hh, w_ih, b_ih, b_hh,
                                                      buf1, stg0, stg1, hbf, hidden);
    } else {
        // fallback: r7-verified serial path
        k_xw_emb<<<M / 32, 256, 0, stream>>>(x, emb, wt, b_ih, b_hh, buf1);
        k_scan<<<NB, 512, 0, stream>>>(w_hh, buf1, hidden);
        float* cur = buf1;
        float* nxt = buf0;
        for (int l = 1; l < NLAYERS; ++l) {
            k_xw  <<<M / 32, 256, 0, stream>>>(cur, wt + l * D * D,
                                               b_ih + l * D, b_hh + l * D, nxt);
            k_scan<<<NB, 512, 0, stream>>>(w_hh + (size_t)l * D * D, nxt,
                                           hidden + l * NB * D);
            float* tswap = cur; cur = nxt; nxt = tswap;
        }
        k_hbf2<<<(M * KA + 255) / 256, 256, 0, stream>>>(cur, hbf);
    }
    k_fc<<<64 * NTILES_N, 256, 0, stream>>>(hbf, fwb, fc_b, out);
}

// Round 17
// 839.793 us; speedup vs baseline: 1.6185x; 1.0176x over previous
//
#include <hip/hip_runtime.h>
#include <hip/hip_bf16.h>

#define VOCAB 10000
#define D 200
#define NLAYERS 3
#define NB 16
#define NS 512
#define M 8192        // NB*NS
#define KA 224        // padded K for A (h3 bf16), 7 * 32
#define KB 232        // padded K for fc_w bf16; odd 16B-chunk count
#define NPADA 10120   // 79*128 = 10112, +8 rows slack for unguarded staging
#define NTILES_N 79
#define NT_TILES 5056 // 4 chunks x 16 b x 79 nt
#define BCHUNKS 3712  // 128 rows x 232 bf16 x 2B / 16B per chunk

// ws layout (bytes)
#define OFF_BUF0 0u                 // 6,553,600  cells1
#define OFF_BUF1 6553600u           // 6,553,600  xw0
#define OFF_WT   13107200u          //   480,000  w_ih transposed
#define OFF_HBF  13587200u          // 3,670,016  h3 bf16 [M][KA]
#define OFF_FWB  17257216u          // 4,695,680  fc_w bf16 [NPADA][KB]
#define OFF_STG1 21952896u          // 6,553,600  cells2
#define OFF_FLG  28506496u          //       128  progress[16] + tile counter
#define WS_NEED  28506624u

typedef __bf16 bf16x8 __attribute__((ext_vector_type(8)));
typedef float  f32x4  __attribute__((ext_vector_type(4)));
typedef unsigned int u32x4 __attribute__((ext_vector_type(4)));
union U64x2 { unsigned long long d[2]; bf16x8 v; };

// ---------------- transpose w_ih ----------------
__global__ void k_wtrans(const float* __restrict__ w_ih, float* __restrict__ wt) {
    int i = blockIdx.x * blockDim.x + threadIdx.x;
    if (i < NLAYERS * D * D) {
        int l = i / (D * D);
        int r = i - l * D * D;
        int k = r / D;
        int n = r - k * D;
        wt[i] = w_ih[l * D * D + n * D + k];
    }
}

// ---------------- fc_w -> bf16 padded ----------------
__global__ void k_fcwbf(const float* __restrict__ fc_w, __bf16* __restrict__ fwb) {
    int i = blockIdx.x * blockDim.x + threadIdx.x;
    if (i < NPADA * KB) {
        int n = i / KB;
        int k = i - n * KB;
        float v = (n < VOCAB && k < D) ? fc_w[(size_t)n * D + k] : 0.f;
        fwb[i] = (__bf16)v;
    }
}

// ---------------- h3 -> bf16 padded (fallback path only) ----------------
__global__ void k_hbf2(const float* __restrict__ h, __bf16* __restrict__ hbf) {
    int i = blockIdx.x * blockDim.x + threadIdx.x;
    if (i < M * KA) {
        int m = i / KA;
        int k = i - m * KA;
        float v = (k < D) ? h[(size_t)m * D + k] : 0.f;
        hbf[i] = (__bf16)v;
    }
}

// ---------------- zero helper ----------------
__global__ void k_zero(u32x4* __restrict__ p, int n4) {
    int i = blockIdx.x * blockDim.x + threadIdx.x;
    if (i < n4) p[i] = u32x4{0u, 0u, 0u, 0u};
}

// ---------------- xw0 = emb[x] @ w_ih0^T + b ----------------
__global__ void k_xw_emb(const int* __restrict__ x, const float* __restrict__ emb,
                         const float* __restrict__ wt,
                         const float* __restrict__ b_ih, const float* __restrict__ b_hh,
                         float* __restrict__ xw) {
    int m0 = blockIdx.x * 32;
    int n  = threadIdx.x;
    if (n >= D) return;
    float bias = b_ih[n] + b_hh[n];
    for (int g = 0; g < 8; ++g) {
        const float* r0 = emb + (size_t)x[m0 + g * 4 + 0] * D;
        const float* r1 = emb + (size_t)x[m0 + g * 4 + 1] * D;
        const float* r2 = emb + (size_t)x[m0 + g * 4 + 2] * D;
        const float* r3 = emb + (size_t)x[m0 + g * 4 + 3] * D;
        float a0 = bias, a1 = bias, a2 = bias, a3 = bias;
        for (int k = 0; k < D; k += 4) {
            #pragma unroll
            for (int kk = 0; kk < 4; ++kk) {
                float w = wt[(k + kk) * D + n];
                a0 += r0[k + kk] * w; a1 += r1[k + kk] * w;
                a2 += r2[k + kk] * w; a3 += r3[k + kk] * w;
            }
        }
        size_t o = (size_t)(m0 + g * 4) * D + n;
        xw[o] = a0; xw[o + D] = a1; xw[o + 2 * D] = a2; xw[o + 3 * D] = a3;
    }
}

// ---------------- generic xw (fallback path) ----------------
__global__ void k_xw(const float* __restrict__ hin, const float* __restrict__ wt,
                     const float* __restrict__ b_ih, const float* __restrict__ b_hh,
                     float* __restrict__ xw) {
    int m0 = blockIdx.x * 32;
    int n  = threadIdx.x;
    if (n >= D) return;
    float bias = b_ih[n] + b_hh[n];
    for (int g = 0; g < 8; ++g) {
        const float* r0 = hin + (size_t)(m0 + g * 4) * D;
        float a0 = bias, a1 = bias, a2 = bias, a3 = bias;
        for (int k = 0; k < D; k += 4) {
            #pragma unroll
            for (int kk = 0; kk < 4; ++kk) {
                float w = wt[(k + kk) * D + n];
                a0 += r0[k + kk] * w; a1 += r0[D + k + kk] * w;
                a2 += r0[2 * D + k + kk] * w; a3 += r0[3 * D + k + kk] * w;
            }
        }
        size_t o = (size_t)(m0 + g * 4) * D + n;
        xw[o] = a0; xw[o + D] = a1; xw[o + 2 * D] = a2; xw[o + 3 * D] = a3;
    }
}

__device__ inline float fast_tanh(float x) {
    x = fminf(fmaxf(x, -15.f), 15.f);
    float e = __expf(2.f * x);
    return (e - 1.f) / (e + 1.f);
}

// ---------------- fused pipe + fc kernel ------------------------------------
// r17 = r16 with the B-staging bug fixed: a 128-row B tile is 128*232 bf16 =
// 3712 16B-chunks (r16 staged only 2048 into a 2048-chunk Bl -> OOB LDS reads
// -> NaN). Bl is now 3712 chunks (59392 B; ~62 KB total LDS, fine at 1
// WG/CU), staged in 8 guarded iterations. Everything else identical to r16:
// WGs 0..47 = r15 pipe; WGs 48..255 = fc workers on an atomic tile queue,
// gated per 128-step chunk on progress[b] (published by pipe-l2 after a
// once-per-chunk vmcnt(0) drain + barrier). Coherence: l2 writes hbf as
// packed-u32 AGENT stores; workers read A via AGENT u64 loads. C-stores
// nontemporal.
__global__ __attribute__((amdgpu_flat_work_group_size(512, 512),
                          amdgpu_waves_per_eu(2, 2)))
void k_fused(const float* __restrict__ whh_all,
             const float* __restrict__ wih_all,
             const float* __restrict__ b_ih,
             const float* __restrict__ b_hh,
             const float* __restrict__ xw0,
             unsigned* __restrict__ cells1,
             unsigned* __restrict__ cells2,
             __bf16* __restrict__ hbf,
             float* __restrict__ hidden,
             const __bf16* __restrict__ fwb,
             const float* __restrict__ fc_b,
             float* __restrict__ out,
             unsigned* __restrict__ progress,
             unsigned* __restrict__ counter) {
    __shared__ float hp0[208], hp1[208], hin[208];
    __shared__ __bf16 Bl[BCHUNKS * 8];          // 59392 B
    __shared__ unsigned tile_s;
    const int bid = blockIdx.x;
    const int t   = threadIdx.x;

    if (bid < 48) {
        // ======================= pipe role (r15 body) =======================
        const int l   = bid >> 4;
        const int b   = bid & 15;
        const int q   = t >> 2, dg = t & 3;
        const bool act = (q < 100);
        const int  rr  = 2 * q + (dg & 1);
        const int  rrl = act ? rr : 0;
        const bool wlane = act && (dg < 2);
        const int  dstart = dg * 52;

        f32x4 wh[2][13], wi[2][13];
        #pragma unroll
        for (int j = 0; j < 2; ++j)
            #pragma unroll
            for (int i = 0; i < 13; ++i) {
                wh[j][i] = f32x4{0.f, 0.f, 0.f, 0.f};
                wi[j][i] = f32x4{0.f, 0.f, 0.f, 0.f};
            }
        if (act) {
            #pragma unroll
            for (int j = 0; j < 2; ++j) {
                const float* wr = whh_all + (size_t)l * D * D + (size_t)(2 * q + j) * D + dstart;
                #pragma unroll
                for (int i = 0; i < 11; ++i) wh[j][i] = *(const f32x4*)(wr + 4 * i);
                if (dg < 3) {
                    wh[j][11] = *(const f32x4*)(wr + 44);
                    wh[j][12] = *(const f32x4*)(wr + 48);
                }
            }
            if (l > 0) {
                #pragma unroll
                for (int j = 0; j < 2; ++j) {
                    const float* wr = wih_all + (size_t)l * D * D + (size_t)(2 * q + j) * D + dstart;
                    #pragma unroll
                    for (int i = 0; i < 11; ++i) wi[j][i] = *(const f32x4*)(wr + 4 * i);
                    if (dg < 3) {
                        wi[j][11] = *(const f32x4*)(wr + 44);
                        wi[j][12] = *(const f32x4*)(wr + 48);
                    }
                }
            }
        }
        float bias = 0.f;
        if (l > 0 && act) bias = b_ih[l * D + rr] + b_hh[l * D + rr];

        if (t < 208) { hp0[t] = 0.f; hp1[t] = 0.f; hin[t] = 0.f; }
        __syncthreads();

        const float* xrow = xw0 + (size_t)b * NS * D;
        const unsigned* sin = (l == 1) ? cells1 + (size_t)b * NS * 200
                            : (l == 2) ? cells2 + (size_t)b * NS * 200 : nullptr;
        unsigned* sout = (l == 0) ? cells1 + (size_t)b * NS * 200
                       : (l == 1) ? cells2 + (size_t)b * NS * 200 : nullptr;

        float hn_prev = 0.f;
        float xv_next = (l == 0) ? xrow[rrl] : 0.f;
        const float* hi = hin + dstart;

        #pragma unroll 1
        for (int s = 0; s < NS; ++s) {
            float xv;
            if (l == 0) {
                xv = xv_next;
                const int sn = (s + 1 < NS) ? s + 1 : NS - 1;
                xv_next = xrow[(size_t)sn * D + rrl];
            } else {
                if (t < 200) {
                    const unsigned* p = sin + (size_t)s * 200 + t;
                    unsigned v = __hip_atomic_load(p, __ATOMIC_RELAXED,
                                                   __HIP_MEMORY_SCOPE_AGENT);
                    while (v == 0u) {
                        __builtin_amdgcn_s_sleep(1);
                        v = __hip_atomic_load(p, __ATOMIC_RELAXED,
                                              __HIP_MEMORY_SCOPE_AGENT);
                    }
                    hin[t] = __builtin_bit_cast(float, ~v);
                }
                asm volatile("s_waitcnt lgkmcnt(0)" ::: "memory");
                __builtin_amdgcn_s_barrier();
                asm volatile("" ::: "memory");
                xv = bias;
            }
            const float* hr = ((s & 1) ? hp1 : hp0) + dstart;
            float* hw = (s & 1) ? hp0 : hp1;
            f32x4 ac0{0.f,0.f,0.f,0.f}, ac1{0.f,0.f,0.f,0.f};
            #pragma unroll
            for (int i = 0; i < 13; ++i) {
                f32x4 h4 = *(const f32x4*)(hr + 4 * i);
                ac0 += h4 * wh[0][i];
                ac1 += h4 * wh[1][i];
            }
            if (l > 0) {
                #pragma unroll
                for (int i = 0; i < 13; ++i) {
                    f32x4 g4 = *(const f32x4*)(hi + 4 * i);
                    ac0 += g4 * wi[0][i];
                    ac1 += g4 * wi[1][i];
                }
            }
            float s0 = (ac0.x + ac0.y) + (ac0.z + ac0.w);
            float s1 = (ac1.x + ac1.y) + (ac1.z + ac1.w);
            s0 += __shfl_xor(s0, 1);  s0 += __shfl_xor(s0, 2);
            s1 += __shfl_xor(s1, 1);  s1 += __shfl_xor(s1, 2);
            float hn = fast_tanh(xv + ((dg & 1) ? s1 : s0));
            hn_prev = hn;
            float hpart = __shfl_xor(hn, 1);       // partner row's h (dg^1)
            if (wlane) {
                hw[rr] = hn;
                if (l < 2) {
                    __hip_atomic_store(sout + (size_t)s * 200 + rr,
                                       ~__builtin_bit_cast(unsigned, hn),
                                       __ATOMIC_RELAXED, __HIP_MEMORY_SCOPE_AGENT);
                }
            }
            if (l == 2 && act && dg == 0) {
                // pack rows (2q, 2q+1) -> one u32 agent store (LLC-coherent)
                unsigned short e0 = __builtin_bit_cast(unsigned short, (__bf16)hn);
                unsigned short e1 = __builtin_bit_cast(unsigned short, (__bf16)hpart);
                unsigned pv = (unsigned)e0 | ((unsigned)e1 << 16);
                __hip_atomic_store((unsigned*)hbf + ((size_t)b * NS + s) * 112 + q,
                                   pv, __ATOMIC_RELAXED, __HIP_MEMORY_SCOPE_AGENT);
            }
            asm volatile("s_waitcnt lgkmcnt(0)" ::: "memory");
            __builtin_amdgcn_s_barrier();
            asm volatile("" ::: "memory");
            if (l == 2 && (s & 127) == 127) {      // publish chunk (4x per scan)
                asm volatile("s_waitcnt vmcnt(0)" ::: "memory");
                __builtin_amdgcn_s_barrier();
                if (t == 0)
                    __hip_atomic_store(progress + b, (unsigned)((s >> 7) + 1),
                                       __ATOMIC_RELAXED, __HIP_MEMORY_SCOPE_AGENT);
            }
        }
        if (wlane) hidden[(size_t)l * NB * D + b * D + rr] = hn_prev;
    } else {
        // ======================= fc worker role =============================
        const int lane = t & 63, wv = t >> 6;
        const int wr = wv >> 2, wc = wv & 3;       // 2x4 waves of 64x32
        const int lr = lane & 15, lq = lane >> 4;
        const unsigned* Au = (const unsigned*)hbf;
        for (;;) {
            if (t == 0) tile_s = atomicAdd(counter, 1u);
            __syncthreads();                        // prev compute done + tile_s visible
            const unsigned tile = tile_s;
            if (tile >= NT_TILES) break;
            const int chunk = tile / 1264;
            const int rem   = tile - chunk * 1264;
            const int nt    = rem >> 4;
            const int b     = rem & 15;
            const int m0    = (b * 4 + chunk) * 128;
            const int n0    = nt * 128;
            {   // stage B tile: 3712 16B-chunks (r16 bug: staged only 2048)
                const u32x4* src = (const u32x4*)(fwb + (size_t)n0 * KB);
                u32x4* dst = (u32x4*)Bl;
                #pragma unroll
                for (int it = 0; it < 8; ++it) {
                    int idx = t + it * 512;
                    if (idx < BCHUNKS) dst[idx] = src[idx];
                }
            }
            if (t == 0) {   // gate on producer progress (1 scalar poll / 1k cyc)
                unsigned pv = __hip_atomic_load(progress + b, __ATOMIC_RELAXED,
                                                __HIP_MEMORY_SCOPE_AGENT);
                while (pv <= (unsigned)chunk) {
                    __builtin_amdgcn_s_sleep(16);
                    pv = __hip_atomic_load(progress + b, __ATOMIC_RELAXED,
                                           __HIP_MEMORY_SCOPE_AGENT);
                }
            }
            __syncthreads();                        // Bl staged + gate passed
            f32x4 acc[4][2] = {};
            #pragma unroll
            for (int ks = 0; ks < 7; ++ks) {
                bf16x8 af[4], bfr[2];
                #pragma unroll
                for (int i = 0; i < 4; ++i) {       // A via AGENT u64 loads
                    size_t arow = (size_t)(m0 + wr * 64 + i * 16 + lr);
                    size_t bo = arow * 112 + (size_t)(ks * 16 + lq * 4);
                    U64x2 u;
                    u.d[0] = __hip_atomic_load((const unsigned long long*)(Au + bo),
                                               __ATOMIC_RELAXED, __HIP_MEMORY_SCOPE_AGENT);
                    u.d[1] = __hip_atomic_load((const unsigned long long*)(Au + bo) + 1,
                                               __ATOMIC_RELAXED, __HIP_MEMORY_SCOPE_AGENT);
                    af[i] = u.v;
                }
                #pragma unroll
                for (int j = 0; j < 2; ++j) {
                    int brow = wc * 32 + j * 16 + lr;
                    bfr[j] = *(const bf16x8*)(Bl + brow * KB + (ks * 4 + lq) * 8);
                }
                #pragma unroll
                for (int i = 0; i < 4; ++i)
                    #pragma unroll
                    for (int j = 0; j < 2; ++j)
                        acc[i][j] = __builtin_amdgcn_mfma_f32_16x16x32_bf16(
                                        af[i], bfr[j], acc[i][j], 0, 0, 0);
            }
            #pragma unroll
            for (int j = 0; j < 2; ++j) {
                int col = n0 + wc * 32 + j * 16 + lr;
                if (col < VOCAB) {
                    float cbias = fc_b[col];
                    #pragma unroll
                    for (int i = 0; i < 4; ++i) {
                        #pragma unroll
                        for (int r = 0; r < 4; ++r) {
                            int row = m0 + wr * 64 + i * 16 + lq * 4 + r;
                            __builtin_nontemporal_store(acc[i][j][r] + cbias,
                                &out[(size_t)row * VOCAB + col]);
                        }
                    }
                }
            }
        }
    }
}

// ---------------- VALU scan (r7-verified, fallback path) ----------------
#define STEP(HR, HW, SIDX)                                                  \
    {                                                                       \
        float xv = xv_next;                                                 \
        int snext = (SIDX) + 1 < NS ? (SIDX) + 1 : NS - 1;                  \
        xv_next = xrow[(size_t)snext * D + rrl];                            \
        f32x4 ac0{0.f,0.f,0.f,0.f}, ac1{0.f,0.f,0.f,0.f};                   \
        _Pragma("unroll")                                                   \
        for (int i = 0; i < 13; ++i) {                                      \
            f32x4 h4 = *(const f32x4*)((HR) + 4 * i);                       \
            ac0 += h4 * w4[0][i];                                           \
            ac1 += h4 * w4[1][i];                                           \
        }                                                                   \
        float s0 = (ac0.x + ac0.y) + (ac0.z + ac0.w);                       \
        float s1 = (ac1.x + ac1.y) + (ac1.z + ac1.w);                       \
        s0 += __shfl_xor(s0, 1);  s0 += __shfl_xor(s0, 2);                  \
        s1 += __shfl_xor(s1, 1);  s1 += __shfl_xor(s1, 2);                  \
        float hn = fast_tanh(xv + ((dg & 1) ? s1 : s0));                    \
        hlast = hn;                                                         \
        if (wlane) {                                                        \
            (HW)[rr] = hn;                                                  \
            xrow[(size_t)(SIDX) * D + rr] = hn;                             \
        }                                                                   \
        __syncthreads();                                                    \
    }

__global__ __attribute__((amdgpu_flat_work_group_size(512, 512),
                          amdgpu_waves_per_eu(2, 2)))
void k_scan(const float* __restrict__ whh,
            float* __restrict__ io,
            float* __restrict__ hidden) {
    __shared__ float hp0[208], hp1[208];
    int t  = threadIdx.x;
    int b  = blockIdx.x;
    int q  = t >> 2;
    int dg = t & 3;
    const bool act = (q < 100);
    const int  rr  = 2 * q + (dg & 1);
    const int  rrl = act ? rr : 0;
    const bool wlane = act && (dg < 2);
    const int  dstart = dg * 52;

    f32x4 w4[2][13];
    #pragma unroll
    for (int j = 0; j < 2; ++j)
        #pragma unroll
        for (int i = 0; i < 13; ++i) w4[j][i] = f32x4{0.f, 0.f, 0.f, 0.f};
    if (act) {
        #pragma unroll
        for (int j = 0; j < 2; ++j) {
            const float* wr = whh + (size_t)(2 * q + j) * D + dstart;
            #pragma unroll
            for (int i = 0; i < 11; ++i) w4[j][i] = *(const f32x4*)(wr + 4 * i);
            if (dg < 3) {
                w4[j][11] = *(const f32x4*)(wr + 44);
                w4[j][12] = *(const f32x4*)(wr + 48);
            }
        }
    }
    if (t < 208) { hp0[t] = 0.f; hp1[t] = 0.f; }
    __syncthreads();

    float* xrow = io + (size_t)b * NS * D;
    const float* hr0 = hp0 + dstart;
    const float* hr1 = hp1 + dstart;
    float xv_next = xrow[rrl];
    float hlast = 0.f;

    #pragma unroll 1
    for (int s2 = 0; s2 < NS / 2; ++s2) {
        STEP(hr0, hp1, 2 * s2)
        STEP(hr1, hp0, 2 * s2 + 1)
    }
    if (wlane) hidden[b * D + rr] = hlast;
}

// ---------------- standalone k_fc (fallback path) ----------------
__global__ __launch_bounds__(256) void k_fc(const __bf16* __restrict__ A,
                                            const __bf16* __restrict__ Bw,
                                            const float* __restrict__ fc_b,
                                            float* __restrict__ Cout) {
    __shared__ __bf16 Bl2[3840 * 8];
    int tid = threadIdx.x;
    int wg  = blockIdx.x;
    int mt  = wg / NTILES_N, nt = wg - mt * NTILES_N;
    int m0  = mt * 128, n0 = nt * 128;
    {
        const u32x4* src = (const u32x4*)(Bw + (size_t)n0 * KB);
        u32x4* dst = (u32x4*)Bl2;
        u32x4 stg[15];
        #pragma unroll
        for (int it = 0; it < 15; ++it) stg[it] = src[tid + it * 256];
        #pragma unroll
        for (int it = 0; it < 15; ++it) dst[tid + it * 256] = stg[it];
    }
    __syncthreads();
    int lane = tid & 63, wv = tid >> 6;
    int wr = wv >> 1, wc = wv & 1;
    int lr = lane & 15, lq = lane >> 4;
    f32x4 acc[4][4] = {};
    #pragma unroll
    for (int ks = 0; ks < 7; ++ks) {
        bf16x8 af[4], bfr[4];
        #pragma unroll
        for (int i = 0; i < 4; ++i) {
            int arow = m0 + wr * 64 + i * 16 + lr;
            af[i] = *(const bf16x8*)(A + (size_t)arow * KA + (ks * 4 + lq) * 8);
            int brow = wc * 64 + i * 16 + lr;
            bfr[i] = *(const bf16x8*)(Bl2 + brow * KB + (ks * 4 + lq) * 8);
        }
        #pragma unroll
        for (int i = 0; i < 4; ++i)
            #pragma unroll
            for (int j = 0; j < 4; ++j)
                acc[i][j] = __builtin_amdgcn_mfma_f32_16x16x32_bf16(af[i], bfr[j],
                                                                   acc[i][j], 0, 0, 0);
    }
    #pragma unroll
    for (int j = 0; j < 4; ++j) {
        int col = n0 + wc * 64 + j * 16 + lr;
        if (col < VOCAB) {
            float bias = fc_b[col];
            #pragma unroll
            for (int i = 0; i < 4; ++i)
                #pragma unroll
                for (int r = 0; r < 4; ++r) {
                    int row = m0 + wr * 64 + i * 16 + lq * 4 + r;
                    __builtin_nontemporal_store(acc[i][j][r] + bias,
                                                &Cout[(size_t)row * VOCAB + col]);
                }
        }
    }
}

extern "C" void kernel_launch(void* const* d_in, const int* in_sizes, int n_in,
                              void* d_out, int out_size, void* d_ws, size_t ws_size,
                              hipStream_t stream) {
    const int*   x    = (const int*)  d_in[0];
    const float* emb  = (const float*)d_in[1];
    const float* w_ih = (const float*)d_in[2];
    const float* w_hh = (const float*)d_in[3];
    const float* b_ih = (const float*)d_in[4];
    const float* b_hh = (const float*)d_in[5];
    const float* fc_w = (const float*)d_in[6];
    const float* fc_b = (const float*)d_in[7];
    float* out    = (float*)d_out;
    float* hidden = out + (size_t)M * VOCAB;

    char* ws = (char*)d_ws;
    float*    buf0 = (float*)(ws + OFF_BUF0);
    float*    buf1 = (float*)(ws + OFF_BUF1);
    float*    wt   = (float*)(ws + OFF_WT);
    __bf16*   hbf  = (__bf16*)(ws + OFF_HBF);
    __bf16*   fwb  = (__bf16*)(ws + OFF_FWB);
    unsigned* stg0 = (unsigned*)(ws + OFF_BUF0);
    unsigned* stg1 = (unsigned*)(ws + OFF_STG1);
    unsigned* flg  = (unsigned*)(ws + OFF_FLG);    // progress[16] + counter

    k_wtrans<<<(NLAYERS * D * D + 255) / 256, 256, 0, stream>>>(w_ih, wt);
    k_fcwbf <<<(NPADA * KB + 255) / 256, 256, 0, stream>>>(fc_w, fwb);

    if (ws_size >= WS_NEED) {
        k_xw_emb<<<M / 32, 256, 0, stream>>>(x, emb, wt, b_ih, b_hh, buf1);
        const int nst4 = NB * NS * 200 / 4;
        const int nhb4 = M * KA * 2 / 16;
        k_zero<<<(nst4 + 255) / 256, 256, 0, stream>>>((u32x4*)stg0, nst4);
        k_zero<<<(nst4 + 255) / 256, 256, 0, stream>>>((u32x4*)stg1, nst4);
        k_zero<<<(nhb4 + 255) / 256, 256, 0, stream>>>((u32x4*)hbf, nhb4);
        k_zero<<<1, 256, 0, stream>>>((u32x4*)flg, 8);
        k_fused<<<256, 512, 0, stream>>>(w_hh, w_ih, b_ih, b_hh, buf1,
                                         stg0, stg1, hbf, hidden,
                                         fwb, fc_b, out, flg, flg + 16);
    } else {
        // fallback: r7-verified serial path
        k_xw_emb<<<M / 32, 256, 0, stream>>>(x, emb, wt, b_ih, b_hh, buf1);
        k_scan<<<NB, 512, 0, stream>>>(w_hh, buf1, hidden);
        float* cur = buf1;
        float* nxt = buf0;
        for (int l = 1; l < NLAYERS; ++l) {
            k_xw  <<<M / 32, 256, 0, stream>>>(cur, wt + l * D * D,
                                               b_ih + l * D, b_hh + l * D, nxt);
            k_scan<<<NB, 512, 0, stream>>>(w_hh + (size_t)l * D * D, nxt,
                                           hidden + l * NB * D);
            float* tswap = cur; cur = nxt; nxt = tswap;
        }
        k_hbf2<<<(M * KA + 255) / 256, 256, 0, stream>>>(cur, hbf);
        k_fc<<<64 * NTILES_N, 256, 0, stream>>>(hbf, fwb, fc_b, out);
    }
}

// Round 18
// 729.391 us; speedup vs baseline: 1.8635x; 1.1514x over previous
//
#include <hip/hip_runtime.h>
#include <hip/hip_bf16.h>

#define VOCAB 10000
#define D 200
#define NLAYERS 3
#define NB 16
#define NS 512
#define M 8192        // NB*NS
#define KA 224        // padded K for A (h3 bf16), 7 * 32
#define KB 232        // padded K for fc_w bf16; odd 16B-chunk count
#define NPADA 10120   // 79*128 = 10112, +8 rows slack for unguarded staging
#define NTILES_N 79
#define NT_TILES 5056 // 4 chunks x 16 b x 79 nt
#define BCHUNKS 3712  // 128 rows x 232 bf16 x 2B / 16B per chunk

// ws layout (bytes)
#define OFF_BUF0 0u                 // 6,553,600  cells1
#define OFF_BUF1 6553600u           // 6,553,600  xw0 (fallback only)
#define OFF_WT   13107200u          //   480,000  w_ih transposed (fallback only)
#define OFF_HBF  13587200u          // 3,670,016  h3 bf16 [M][KA]
#define OFF_FWB  17257216u          // 4,695,680  fc_w bf16 [NPADA][KB]
#define OFF_STG1 21952896u          // 6,553,600  cells2
#define OFF_FLG  28506496u          //       128  progress[16] + tile counter
#define WS_NEED  28506624u

typedef __bf16 bf16x8 __attribute__((ext_vector_type(8)));
typedef float  f32x4  __attribute__((ext_vector_type(4)));
typedef unsigned int u32x4 __attribute__((ext_vector_type(4)));
union U64x2 { unsigned long long d[2]; bf16x8 v; };

// ---------------- one-shot prep: fcwbf + zero cells + zero flags -------------
__global__ void k_prep(const float* __restrict__ fc_w, __bf16* __restrict__ fwb,
                       u32x4* __restrict__ c1, u32x4* __restrict__ c2,
                       unsigned* __restrict__ flg) {
    const int i = blockIdx.x * blockDim.x + threadIdx.x;
    const int stride = gridDim.x * blockDim.x;
    for (int j = i; j < NPADA * KB; j += stride) {
        int n = j / KB;
        int k = j - n * KB;
        float v = (n < VOCAB && k < D) ? fc_w[(size_t)n * D + k] : 0.f;
        fwb[j] = (__bf16)v;
    }
    const int nst4 = NB * NS * 200 / 4;
    for (int j = i; j < nst4; j += stride) {
        c1[j] = u32x4{0u, 0u, 0u, 0u};
        c2[j] = u32x4{0u, 0u, 0u, 0u};
    }
    if (i < 32) flg[i] = 0u;
}

// ---------------- fallback-path helpers (unchanged, r7-verified) -------------
__global__ void k_wtrans(const float* __restrict__ w_ih, float* __restrict__ wt) {
    int i = blockIdx.x * blockDim.x + threadIdx.x;
    if (i < NLAYERS * D * D) {
        int l = i / (D * D);
        int r = i - l * D * D;
        int k = r / D;
        int n = r - k * D;
        wt[i] = w_ih[l * D * D + n * D + k];
    }
}

__global__ void k_fcwbf(const float* __restrict__ fc_w, __bf16* __restrict__ fwb) {
    int i = blockIdx.x * blockDim.x + threadIdx.x;
    if (i < NPADA * KB) {
        int n = i / KB;
        int k = i - n * KB;
        float v = (n < VOCAB && k < D) ? fc_w[(size_t)n * D + k] : 0.f;
        fwb[i] = (__bf16)v;
    }
}

__global__ void k_hbf2(const float* __restrict__ h, __bf16* __restrict__ hbf) {
    int i = blockIdx.x * blockDim.x + threadIdx.x;
    if (i < M * KA) {
        int m = i / KA;
        int k = i - m * KA;
        float v = (k < D) ? h[(size_t)m * D + k] : 0.f;
        hbf[i] = (__bf16)v;
    }
}

__global__ void k_xw_emb(const int* __restrict__ x, const float* __restrict__ emb,
                         const float* __restrict__ wt,
                         const float* __restrict__ b_ih, const float* __restrict__ b_hh,
                         float* __restrict__ xw) {
    int m0 = blockIdx.x * 32;
    int n  = threadIdx.x;
    if (n >= D) return;
    float bias = b_ih[n] + b_hh[n];
    for (int g = 0; g < 8; ++g) {
        const float* r0 = emb + (size_t)x[m0 + g * 4 + 0] * D;
        const float* r1 = emb + (size_t)x[m0 + g * 4 + 1] * D;
        const float* r2 = emb + (size_t)x[m0 + g * 4 + 2] * D;
        const float* r3 = emb + (size_t)x[m0 + g * 4 + 3] * D;
        float a0 = bias, a1 = bias, a2 = bias, a3 = bias;
        for (int k = 0; k < D; k += 4) {
            #pragma unroll
            for (int kk = 0; kk < 4; ++kk) {
                float w = wt[(k + kk) * D + n];
                a0 += r0[k + kk] * w; a1 += r1[k + kk] * w;
                a2 += r2[k + kk] * w; a3 += r3[k + kk] * w;
            }
        }
        size_t o = (size_t)(m0 + g * 4) * D + n;
        xw[o] = a0; xw[o + D] = a1; xw[o + 2 * D] = a2; xw[o + 3 * D] = a3;
    }
}

__global__ void k_xw(const float* __restrict__ hin, const float* __restrict__ wt,
                     const float* __restrict__ b_ih, const float* __restrict__ b_hh,
                     float* __restrict__ xw) {
    int m0 = blockIdx.x * 32;
    int n  = threadIdx.x;
    if (n >= D) return;
    float bias = b_ih[n] + b_hh[n];
    for (int g = 0; g < 8; ++g) {
        const float* r0 = hin + (size_t)(m0 + g * 4) * D;
        float a0 = bias, a1 = bias, a2 = bias, a3 = bias;
        for (int k = 0; k < D; k += 4) {
            #pragma unroll
            for (int kk = 0; kk < 4; ++kk) {
                float w = wt[(k + kk) * D + n];
                a0 += r0[k + kk] * w; a1 += r0[D + k + kk] * w;
                a2 += r0[2 * D + k + kk] * w; a3 += r0[3 * D + k + kk] * w;
            }
        }
        size_t o = (size_t)(m0 + g * 4) * D + n;
        xw[o] = a0; xw[o + D] = a1; xw[o + 2 * D] = a2; xw[o + 3 * D] = a3;
    }
}

__device__ inline float fast_tanh(float x) {
    x = fminf(fmaxf(x, -15.f), 15.f);
    float e = __expf(2.f * x);
    return (e - 1.f) / (e + 1.f);
}

// ---------------- fused pipe + fc kernel ------------------------------------
// r18 vs r17 (840us, passed): the launch chain collapses 8 -> 2. (1) pipe-l0
// now computes xw0 IN-STREAM: its previously-idle wi slot holds w_ih0 rows,
// and hin is staged from emb[x[b,s]] (token row, 800B coalesced) prefetched
// ONE STEP AHEAD into a register — tokens are recurrence-independent and the
// lgkm-only barriers don't drain vmcnt, so the gather hides under the FMA
// block. l0: 104 -> 208 FMA/lane = same cost as l1/l2 => pipe rate unchanged.
// Deletes k_wtrans + k_xw_emb + buf1 from the hot path. (2) k_prep fuses
// fcwbf + cell/flag zeroing; hbf pad cols written in-kernel by l2 (agent u32
// stores, coherent with workers' agent loads) — deletes all k_zero launches.
// Worker role and gating byte-identical to r17.
__global__ __attribute__((amdgpu_flat_work_group_size(512, 512),
                          amdgpu_waves_per_eu(2, 2)))
void k_fused(const float* __restrict__ whh_all,
             const float* __restrict__ wih_all,
             const float* __restrict__ b_ih,
             const float* __restrict__ b_hh,
             const int* __restrict__ x,
             const float* __restrict__ emb,
             unsigned* __restrict__ cells1,
             unsigned* __restrict__ cells2,
             __bf16* __restrict__ hbf,
             float* __restrict__ hidden,
             const __bf16* __restrict__ fwb,
             const float* __restrict__ fc_b,
             float* __restrict__ out,
             unsigned* __restrict__ progress,
             unsigned* __restrict__ counter) {
    __shared__ float hp0[208], hp1[208], hin[208];
    __shared__ int xtok[NS];                    // 2 KB, l0 only
    __shared__ __bf16 Bl[BCHUNKS * 8];          // 59392 B
    __shared__ unsigned tile_s;
    const int bid = blockIdx.x;
    const int t   = threadIdx.x;

    if (bid < 48) {
        // ======================= pipe role =======================
        const int l   = bid >> 4;
        const int b   = bid & 15;
        const int q   = t >> 2, dg = t & 3;
        const bool act = (q < 100);
        const int  rr  = 2 * q + (dg & 1);
        const bool wlane = act && (dg < 2);
        const int  dstart = dg * 52;

        f32x4 wh[2][13], wi[2][13];
        #pragma unroll
        for (int j = 0; j < 2; ++j)
            #pragma unroll
            for (int i = 0; i < 13; ++i) {
                wh[j][i] = f32x4{0.f, 0.f, 0.f, 0.f};
                wi[j][i] = f32x4{0.f, 0.f, 0.f, 0.f};
            }
        if (act) {
            #pragma unroll
            for (int j = 0; j < 2; ++j) {
                const float* wr = whh_all + (size_t)l * D * D + (size_t)(2 * q + j) * D + dstart;
                #pragma unroll
                for (int i = 0; i < 11; ++i) wh[j][i] = *(const f32x4*)(wr + 4 * i);
                if (dg < 3) {
                    wh[j][11] = *(const f32x4*)(wr + 44);
                    wh[j][12] = *(const f32x4*)(wr + 48);
                }
            }
            // ALL layers load wi now (l0 uses w_ih layer 0 for in-stream xw)
            #pragma unroll
            for (int j = 0; j < 2; ++j) {
                const float* wr = wih_all + (size_t)l * D * D + (size_t)(2 * q + j) * D + dstart;
                #pragma unroll
                for (int i = 0; i < 11; ++i) wi[j][i] = *(const f32x4*)(wr + 4 * i);
                if (dg < 3) {
                    wi[j][11] = *(const f32x4*)(wr + 44);
                    wi[j][12] = *(const f32x4*)(wr + 48);
                }
            }
        }
        float bias = 0.f;
        if (act) bias = b_ih[l * D + rr] + b_hh[l * D + rr];

        if (t < 208) { hp0[t] = 0.f; hp1[t] = 0.f; hin[t] = 0.f; }
        if (l == 0)
            for (int i = t; i < NS; i += 512) xtok[i] = x[b * NS + i];
        __syncthreads();

        const unsigned* sin = (l == 1) ? cells1 + (size_t)b * NS * 200
                            : (l == 2) ? cells2 + (size_t)b * NS * 200 : nullptr;
        unsigned* sout = (l == 0) ? cells1 + (size_t)b * NS * 200
                       : (l == 1) ? cells2 + (size_t)b * NS * 200 : nullptr;

        float hn_prev = 0.f;
        float ereg = 0.f;
        if (l == 0 && t < 200) ereg = emb[(size_t)xtok[0] * D + t];  // prefetch s=0
        const float* hi = hin + dstart;

        #pragma unroll 1
        for (int s = 0; s < NS; ++s) {
            // stage hin: l0 <- prefetched emb row; l>0 <- spin on cell
            if (t < 200) {
                if (l == 0) {
                    hin[t] = ereg;
                } else {
                    const unsigned* p = sin + (size_t)s * 200 + t;
                    unsigned v = __hip_atomic_load(p, __ATOMIC_RELAXED,
                                                   __HIP_MEMORY_SCOPE_AGENT);
                    while (v == 0u) {
                        __builtin_amdgcn_s_sleep(1);
                        v = __hip_atomic_load(p, __ATOMIC_RELAXED,
                                              __HIP_MEMORY_SCOPE_AGENT);
                    }
                    hin[t] = __builtin_bit_cast(float, ~v);
                }
            }
            asm volatile("s_waitcnt lgkmcnt(0)" ::: "memory");
            __builtin_amdgcn_s_barrier();
            asm volatile("" ::: "memory");
            // issue next emb-row prefetch (consumed next iter; flies under FMAs)
            if (l == 0 && t < 200) {
                const int sn = (s + 1 < NS) ? s + 1 : NS - 1;
                ereg = emb[(size_t)xtok[sn] * D + t];
            }
            const float* hr = ((s & 1) ? hp1 : hp0) + dstart;
            float* hw = (s & 1) ? hp0 : hp1;
            f32x4 ac0{0.f,0.f,0.f,0.f}, ac1{0.f,0.f,0.f,0.f};
            #pragma unroll
            for (int i = 0; i < 13; ++i) {
                f32x4 h4 = *(const f32x4*)(hr + 4 * i);
                ac0 += h4 * wh[0][i];
                ac1 += h4 * wh[1][i];
            }
            #pragma unroll
            for (int i = 0; i < 13; ++i) {
                f32x4 g4 = *(const f32x4*)(hi + 4 * i);
                ac0 += g4 * wi[0][i];
                ac1 += g4 * wi[1][i];
            }
            float s0 = (ac0.x + ac0.y) + (ac0.z + ac0.w);
            float s1 = (ac1.x + ac1.y) + (ac1.z + ac1.w);
            s0 += __shfl_xor(s0, 1);  s0 += __shfl_xor(s0, 2);
            s1 += __shfl_xor(s1, 1);  s1 += __shfl_xor(s1, 2);
            float hn = fast_tanh(bias + ((dg & 1) ? s1 : s0));
            hn_prev = hn;
            float hpart = __shfl_xor(hn, 1);       // partner row's h (dg^1)
            if (wlane) {
                hw[rr] = hn;
                if (l < 2) {
                    __hip_atomic_store(sout + (size_t)s * 200 + rr,
                                       ~__builtin_bit_cast(unsigned, hn),
                                       __ATOMIC_RELAXED, __HIP_MEMORY_SCOPE_AGENT);
                }
            }
            if (l == 2) {
                if (act && dg == 0) {
                    // pack rows (2q, 2q+1) -> one u32 agent store (LLC-coherent)
                    unsigned short e0 = __builtin_bit_cast(unsigned short, (__bf16)hn);
                    unsigned short e1 = __builtin_bit_cast(unsigned short, (__bf16)hpart);
                    unsigned pv = (unsigned)e0 | ((unsigned)e1 << 16);
                    __hip_atomic_store((unsigned*)hbf + ((size_t)b * NS + s) * 112 + q,
                                       pv, __ATOMIC_RELAXED, __HIP_MEMORY_SCOPE_AGENT);
                } else if (t >= 400 && t < 412) {
                    // pad cols 200..223 = 0 (agent store, coherent w/ workers)
                    __hip_atomic_store((unsigned*)hbf + ((size_t)b * NS + s) * 112
                                           + 100 + (t - 400),
                                       0u, __ATOMIC_RELAXED, __HIP_MEMORY_SCOPE_AGENT);
                }
            }
            asm volatile("s_waitcnt lgkmcnt(0)" ::: "memory");
            __builtin_amdgcn_s_barrier();
            asm volatile("" ::: "memory");
            if (l == 2 && (s & 127) == 127) {      // publish chunk (4x per scan)
                asm volatile("s_waitcnt vmcnt(0)" ::: "memory");
                __builtin_amdgcn_s_barrier();
                if (t == 0)
                    __hip_atomic_store(progress + b, (unsigned)((s >> 7) + 1),
                                       __ATOMIC_RELAXED, __HIP_MEMORY_SCOPE_AGENT);
            }
        }
        if (wlane) hidden[(size_t)l * NB * D + b * D + rr] = hn_prev;
    } else {
        // ======================= fc worker role (r17-identical) =============
        const int lane = t & 63, wv = t >> 6;
        const int wr = wv >> 2, wc = wv & 3;       // 2x4 waves of 64x32
        const int lr = lane & 15, lq = lane >> 4;
        const unsigned* Au = (const unsigned*)hbf;
        for (;;) {
            if (t == 0) tile_s = atomicAdd(counter, 1u);
            __syncthreads();                        // prev compute done + tile_s visible
            const unsigned tile = tile_s;
            if (tile >= NT_TILES) break;
            const int chunk = tile / 1264;
            const int rem   = tile - chunk * 1264;
            const int nt    = rem >> 4;
            const int b     = rem & 15;
            const int m0    = (b * 4 + chunk) * 128;
            const int n0    = nt * 128;
            {   // stage B tile: 3712 16B-chunks
                const u32x4* src = (const u32x4*)(fwb + (size_t)n0 * KB);
                u32x4* dst = (u32x4*)Bl;
                #pragma unroll
                for (int it = 0; it < 8; ++it) {
                    int idx = t + it * 512;
                    if (idx < BCHUNKS) dst[idx] = src[idx];
                }
            }
            if (t == 0) {   // gate on producer progress
                unsigned pv = __hip_atomic_load(progress + b, __ATOMIC_RELAXED,
                                                __HIP_MEMORY_SCOPE_AGENT);
                while (pv <= (unsigned)chunk) {
                    __builtin_amdgcn_s_sleep(16);
                    pv = __hip_atomic_load(progress + b, __ATOMIC_RELAXED,
                                           __HIP_MEMORY_SCOPE_AGENT);
                }
            }
            __syncthreads();                        // Bl staged + gate passed
            f32x4 acc[4][2] = {};
            #pragma unroll
            for (int ks = 0; ks < 7; ++ks) {
                bf16x8 af[4], bfr[2];
                #pragma unroll
                for (int i = 0; i < 4; ++i) {       // A via AGENT u64 loads
                    size_t arow = (size_t)(m0 + wr * 64 + i * 16 + lr);
                    size_t bo = arow * 112 + (size_t)(ks * 16 + lq * 4);
                    U64x2 u;
                    u.d[0] = __hip_atomic_load((const unsigned long long*)(Au + bo),
                                               __ATOMIC_RELAXED, __HIP_MEMORY_SCOPE_AGENT);
                    u.d[1] = __hip_atomic_load((const unsigned long long*)(Au + bo) + 1,
                                               __ATOMIC_RELAXED, __HIP_MEMORY_SCOPE_AGENT);
                    af[i] = u.v;
                }
                #pragma unroll
                for (int j = 0; j < 2; ++j) {
                    int brow = wc * 32 + j * 16 + lr;
                    bfr[j] = *(const bf16x8*)(Bl + brow * KB + (ks * 4 + lq) * 8);
                }
                #pragma unroll
                for (int i = 0; i < 4; ++i)
                    #pragma unroll
                    for (int j = 0; j < 2; ++j)
                        acc[i][j] = __builtin_amdgcn_mfma_f32_16x16x32_bf16(
                                        af[i], bfr[j], acc[i][j], 0, 0, 0);
            }
            #pragma unroll
            for (int j = 0; j < 2; ++j) {
                int col = n0 + wc * 32 + j * 16 + lr;
                if (col < VOCAB) {
                    float cbias = fc_b[col];
                    #pragma unroll
                    for (int i = 0; i < 4; ++i) {
                        #pragma unroll
                        for (int r = 0; r < 4; ++r) {
                            int row = m0 + wr * 64 + i * 16 + lq * 4 + r;
                            __builtin_nontemporal_store(acc[i][j][r] + cbias,
                                &out[(size_t)row * VOCAB + col]);
                        }
                    }
                }
            }
        }
    }
}

// ---------------- VALU scan (r7-verified, fallback path) ----------------
#define STEP(HR, HW, SIDX)                                                  \
    {                                                                       \
        float xv = xv_next;                                                 \
        int snext = (SIDX) + 1 < NS ? (SIDX) + 1 : NS - 1;                  \
        xv_next = xrow[(size_t)snext * D + rrl];                            \
        f32x4 ac0{0.f,0.f,0.f,0.f}, ac1{0.f,0.f,0.f,0.f};                   \
        _Pragma("unroll")                                                   \
        for (int i = 0; i < 13; ++i) {                                      \
            f32x4 h4 = *(const f32x4*)((HR) + 4 * i);                       \
            ac0 += h4 * w4[0][i];                                           \
            ac1 += h4 * w4[1][i];                                           \
        }                                                                   \
        float s0 = (ac0.x + ac0.y) + (ac0.z + ac0.w);                       \
        float s1 = (ac1.x + ac1.y) + (ac1.z + ac1.w);                       \
        s0 += __shfl_xor(s0, 1);  s0 += __shfl_xor(s0, 2);                  \
        s1 += __shfl_xor(s1, 1);  s1 += __shfl_xor(s1, 2);                  \
        float hn = fast_tanh(xv + ((dg & 1) ? s1 : s0));                    \
        hlast = hn;                                                         \
        if (wlane) {                                                        \
            (HW)[rr] = hn;                                                  \
            xrow[(size_t)(SIDX) * D + rr] = hn;                             \
        }                                                                   \
        __syncthreads();                                                    \
    }

__global__ __attribute__((amdgpu_flat_work_group_size(512, 512),
                          amdgpu_waves_per_eu(2, 2)))
void k_scan(const float* __restrict__ whh,
            float* __restrict__ io,
            float* __restrict__ hidden) {
    __shared__ float hp0[208], hp1[208];
    int t  = threadIdx.x;
    int b  = blockIdx.x;
    int q  = t >> 2;
    int dg = t & 3;
    const bool act = (q < 100);
    const int  rr  = 2 * q + (dg & 1);
    const int  rrl = act ? rr : 0;
    const bool wlane = act && (dg < 2);
    const int  dstart = dg * 52;

    f32x4 w4[2][13];
    #pragma unroll
    for (int j = 0; j < 2; ++j)
        #pragma unroll
        for (int i = 0; i < 13; ++i) w4[j][i] = f32x4{0.f, 0.f, 0.f, 0.f};
    if (act) {
        #pragma unroll
        for (int j = 0; j < 2; ++j) {
            const float* wr = whh + (size_t)(2 * q + j) * D + dstart;
            #pragma unroll
            for (int i = 0; i < 11; ++i) w4[j][i] = *(const f32x4*)(wr + 4 * i);
            if (dg < 3) {
                w4[j][11] = *(const f32x4*)(wr + 44);
                w4[j][12] = *(const f32x4*)(wr + 48);
            }
        }
    }
    if (t < 208) { hp0[t] = 0.f; hp1[t] = 0.f; }
    __syncthreads();

    float* xrow = io + (size_t)b * NS * D;
    const float* hr0 = hp0 + dstart;
    const float* hr1 = hp1 + dstart;
    float xv_next = xrow[rrl];
    float hlast = 0.f;

    #pragma unroll 1
    for (int s2 = 0; s2 < NS / 2; ++s2) {
        STEP(hr0, hp1, 2 * s2)
        STEP(hr1, hp0, 2 * s2 + 1)
    }
    if (wlane) hidden[b * D + rr] = hlast;
}

// ---------------- standalone k_fc (fallback path) ----------------
__global__ __launch_bounds__(256) void k_fc(const __bf16* __restrict__ A,
                                            const __bf16* __restrict__ Bw,
                                            const float* __restrict__ fc_b,
                                            float* __restrict__ Cout) {
    __shared__ __bf16 Bl2[3840 * 8];
    int tid = threadIdx.x;
    int wg  = blockIdx.x;
    int mt  = wg / NTILES_N, nt = wg - mt * NTILES_N;
    int m0  = mt * 128, n0 = nt * 128;
    {
        const u32x4* src = (const u32x4*)(Bw + (size_t)n0 * KB);
        u32x4* dst = (u32x4*)Bl2;
        u32x4 stg[15];
        #pragma unroll
        for (int it = 0; it < 15; ++it) stg[it] = src[tid + it * 256];
        #pragma unroll
        for (int it = 0; it < 15; ++it) dst[tid + it * 256] = stg[it];
    }
    __syncthreads();
    int lane = tid & 63, wv = tid >> 6;
    int wr = wv >> 1, wc = wv & 1;
    int lr = lane & 15, lq = lane >> 4;
    f32x4 acc[4][4] = {};
    #pragma unroll
    for (int ks = 0; ks < 7; ++ks) {
        bf16x8 af[4], bfr[4];
        #pragma unroll
        for (int i = 0; i < 4; ++i) {
            int arow = m0 + wr * 64 + i * 16 + lr;
            af[i] = *(const bf16x8*)(A + (size_t)arow * KA + (ks * 4 + lq) * 8);
            int brow = wc * 64 + i * 16 + lr;
            bfr[i] = *(const bf16x8*)(Bl2 + brow * KB + (ks * 4 + lq) * 8);
        }
        #pragma unroll
        for (int i = 0; i < 4; ++i)
            #pragma unroll
            for (int j = 0; j < 4; ++j)
                acc[i][j] = __builtin_amdgcn_mfma_f32_16x16x32_bf16(af[i], bfr[j],
                                                                   acc[i][j], 0, 0, 0);
    }
    #pragma unroll
    for (int j = 0; j < 4; ++j) {
        int col = n0 + wc * 64 + j * 16 + lr;
        if (col < VOCAB) {
            float bias = fc_b[col];
            #pragma unroll
            for (int i = 0; i < 4; ++i)
                #pragma unroll
                for (int r = 0; r < 4; ++r) {
                    int row = m0 + wr * 64 + i * 16 + lq * 4 + r;
                    __builtin_nontemporal_store(acc[i][j][r] + bias,
                                                &Cout[(size_t)row * VOCAB + col]);
                }
        }
    }
}

extern "C" void kernel_launch(void* const* d_in, const int* in_sizes, int n_in,
                              void* d_out, int out_size, void* d_ws, size_t ws_size,
                              hipStream_t stream) {
    const int*   x    = (const int*)  d_in[0];
    const float* emb  = (const float*)d_in[1];
    const float* w_ih = (const float*)d_in[2];
    const float* w_hh = (const float*)d_in[3];
    const float* b_ih = (const float*)d_in[4];
    const float* b_hh = (const float*)d_in[5];
    const float* fc_w = (const float*)d_in[6];
    const float* fc_b = (const float*)d_in[7];
    float* out    = (float*)d_out;
    float* hidden = out + (size_t)M * VOCAB;

    char* ws = (char*)d_ws;
    float*    buf0 = (float*)(ws + OFF_BUF0);
    float*    buf1 = (float*)(ws + OFF_BUF1);
    float*    wt   = (float*)(ws + OFF_WT);
    __bf16*   hbf  = (__bf16*)(ws + OFF_HBF);
    __bf16*   fwb  = (__bf16*)(ws + OFF_FWB);
    unsigned* stg0 = (unsigned*)(ws + OFF_BUF0);
    unsigned* stg1 = (unsigned*)(ws + OFF_STG1);
    unsigned* flg  = (unsigned*)(ws + OFF_FLG);    // progress[16] + counter

    if (ws_size >= WS_NEED) {
        k_prep<<<2048, 256, 0, stream>>>(fc_w, fwb, (u32x4*)stg0, (u32x4*)stg1, flg);
        k_fused<<<256, 512, 0, stream>>>(w_hh, w_ih, b_ih, b_hh, x, emb,
                                         stg0, stg1, hbf, hidden,
                                         fwb, fc_b, out, flg, flg + 16);
    } else {
        // fallback: r7-verified serial path
        k_wtrans<<<(NLAYERS * D * D + 255) / 256, 256, 0, stream>>>(w_ih, wt);
        k_fcwbf <<<(NPADA * KB + 255) / 256, 256, 0, stream>>>(fc_w, fwb);
        k_xw_emb<<<M / 32, 256, 0, stream>>>(x, emb, wt, b_ih, b_hh, buf1);
        k_scan<<<NB, 512, 0, stream>>>(w_hh, buf1, hidden);
        float* cur = buf1;
        float* nxt = buf0;
        for (int l = 1; l < NLAYERS; ++l) {
            k_xw  <<<M / 32, 256, 0, stream>>>(cur, wt + l * D * D,
                                               b_ih + l * D, b_hh + l * D, nxt);
            k_scan<<<NB, 512, 0, stream>>>(w_hh + (size_t)l * D * D, nxt,
                                           hidden + l * NB * D);
            float* tswap = cur; cur = nxt; nxt = tswap;
        }
        k_hbf2<<<(M * KA + 255) / 256, 256, 0, stream>>>(cur, hbf);
        k_fc<<<64 * NTILES_N, 256, 0, stream>>>(hbf, fwb, fc_b, out);
    }
}